// Round 1
// baseline (5470.350 us; speedup 1.0000x reference)
//
#include <hip/hip_runtime.h>
#include <cstdint>
#include <cstddef>

// ---------------- constants ----------------
#define NN 4096          // nodes
#define DH 128           // H1 == H2 == GRU_H
#define TP 4

// ---------------- pack adjacency into bitmask ----------------
__global__ __launch_bounds__(256) void pack_mask_k(const int* __restrict__ adj,
                                                   unsigned long long* __restrict__ mb) {
  int w = blockIdx.x * 4 + (threadIdx.x >> 6);
  int lane = threadIdx.x & 63;
  int v = adj[(size_t)w * 64 + lane];
  unsigned long long bits = __ballot(v > 0);
  if (lane == 0) mb[w] = bits;
}

// ---------------- zero fill ----------------
__global__ __launch_bounds__(256) void fill0_k(float* __restrict__ p, int n) {
  int i = blockIdx.x * 256 + threadIdx.x;
  if (i < n) p[i] = 0.f;
}

// ---------------- generic fp32 GEMM: C = act(A@B + bias) ----------------
// ACT: 0 = none, 1 = leaky(0.01)
template <int ACT>
__global__ __launch_bounds__(256) void gemm_k(const float* __restrict__ A, const float* __restrict__ B,
                                              const float* __restrict__ bias, float* __restrict__ C,
                                              int M, int N, int K) {
  __shared__ float As[16][72];   // [k][m], pad 72 -> 16B-aligned rows, mild write conflict only
  __shared__ float Bs[16][64];   // [k][n]
  const int tid = threadIdx.x;
  const int tx = tid & 15, ty = tid >> 4;
  const int bm = blockIdx.y * 64, bn = blockIdx.x * 64;
  const int kk = tid & 15, mbase = tid >> 4;
  const int nb = tid & 63, kb = tid >> 6;
  float acc[4][4] = {};
  for (int k0 = 0; k0 < K; k0 += 16) {
#pragma unroll
    for (int i = 0; i < 4; i++) {
      int m = mbase + i * 16;
      int gk = k0 + kk;
      As[kk][m] = (gk < K) ? A[(size_t)(bm + m) * K + gk] : 0.f;
    }
#pragma unroll
    for (int i = 0; i < 4; i++) {
      int kk2 = kb + i * 4;
      int gk = k0 + kk2;
      Bs[kk2][nb] = (gk < K && (bn + nb) < N) ? B[(size_t)gk * N + (bn + nb)] : 0.f;
    }
    __syncthreads();
#pragma unroll
    for (int k = 0; k < 16; k++) {
      float4 av = *(const float4*)&As[k][ty * 4];
      float4 bv = *(const float4*)&Bs[k][tx * 4];
      float a[4] = {av.x, av.y, av.z, av.w};
      float b[4] = {bv.x, bv.y, bv.z, bv.w};
#pragma unroll
      for (int i = 0; i < 4; i++)
#pragma unroll
        for (int j = 0; j < 4; j++) acc[i][j] += a[i] * b[j];
    }
    __syncthreads();
  }
  int cn = bn + tx * 4;
  if (cn + 3 < N) {
    float bv[4] = {0.f, 0.f, 0.f, 0.f};
    if (bias) {
      float4 t = *(const float4*)&bias[cn];
      bv[0] = t.x; bv[1] = t.y; bv[2] = t.z; bv[3] = t.w;
    }
#pragma unroll
    for (int i = 0; i < 4; i++) {
      int row = bm + ty * 4 + i;
      float o[4];
#pragma unroll
      for (int j = 0; j < 4; j++) {
        float v = acc[i][j] + bv[j];
        if (ACT == 1) v = (v >= 0.f) ? v : 0.01f * v;
        o[j] = v;
      }
      float4 st = {o[0], o[1], o[2], o[3]};
      *(float4*)&C[(size_t)row * N + cn] = st;
    }
  }
}

// ---------------- el/er: two dot products per row ----------------
__global__ __launch_bounds__(256) void eler_k(const float* __restrict__ h, const float* __restrict__ a,
                                              float* __restrict__ el, float* __restrict__ er) {
  int row = blockIdx.x * 4 + (threadIdx.x >> 6);
  int lane = threadIdx.x & 63;
  const float* hr = h + (size_t)row * DH;
  float h0 = hr[lane], h1 = hr[lane + 64];
  float pe = h0 * a[lane] + h1 * a[lane + 64];
  float pr = h0 * a[128 + lane] + h1 * a[192 + lane];
#pragma unroll
  for (int off = 32; off >= 1; off >>= 1) {
    pe += __shfl_xor(pe, off, 64);
    pr += __shfl_xor(pr, off, 64);
  }
  if (lane == 0) { el[row] = pe; er[row] = pr; }
}

// ---------------- fused GAT attention ----------------
// out_row = headw * ( rownorm(leaky(softmax_masked(leaky(el_i+er_j)) @ h, 0.2)) + b )
// accum=0 -> store, accum=1 -> add (head mean)
__global__ __launch_bounds__(256) void gat_attn_k(const float* __restrict__ h, const float* __restrict__ el,
                                                  const float* __restrict__ er,
                                                  const unsigned long long* __restrict__ mb,
                                                  const float* __restrict__ bvec, float* __restrict__ out,
                                                  float headw, int accum) {
  __shared__ float hs[64][DH];   // 32 KB j-tile of h
  __shared__ float ws[8][64];    // softmax weights for the tile
  __shared__ float m_s[8], z_s[8], el_s[8];
  const int tid = threadIdx.x;
  const int r = tid >> 5;        // row group 0..7
  const int lane = tid & 31;
  const int row0 = blockIdx.x * 8;
  const int row = row0 + r;
  if (tid < 8) el_s[tid] = el[row0 + tid];

  // ---- phase 1: masked online softmax stats (m, Z) per row ----
  float m = -INFINITY, Z = 0.f;
  const float elr = el[row];
  const unsigned long long* mrow = mb + (size_t)row * 64;
  for (int j = lane; j < NN; j += 32) {
    unsigned long long w = mrow[j >> 6];
    float s = elr + er[j];
    s = (s >= 0.f) ? s : 0.2f * s;
    s = ((w >> (j & 63)) & 1ull) ? s : -9e15f;
    float nm = fmaxf(m, s);
    Z = Z * __expf(m - nm) + __expf(s - nm);
    m = nm;
  }
#pragma unroll
  for (int off = 1; off < 32; off <<= 1) {
    float m2 = __shfl_xor(m, off, 64);
    float Z2 = __shfl_xor(Z, off, 64);
    float nm = fmaxf(m, m2);
    Z = Z * __expf(m - nm) + Z2 * __expf(m2 - nm);
    m = nm;
  }
  if (lane == 0) { m_s[r] = m; z_s[r] = Z; }
  __syncthreads();

  // ---- phase 2: weighted accumulation ----
  float acc0 = 0.f, acc1 = 0.f, acc2 = 0.f, acc3 = 0.f;
  const int c4 = lane * 4;
  for (int jt = 0; jt < NN; jt += 64) {
#pragma unroll
    for (int i = 0; i < 8; i++) {
      int idx = tid + i * 256;               // 0..2047 float4 slots
      int hr_ = idx >> 5, hc = (idx & 31) * 4;
      *(float4*)&hs[hr_][hc] = *(const float4*)&h[(size_t)(jt + hr_) * DH + hc];
    }
#pragma unroll
    for (int i = 0; i < 2; i++) {
      int idx = tid + i * 256;               // 0..511
      int wr = idx >> 6, jj = idx & 63;
      int j = jt + jj;
      unsigned long long wb = mb[(size_t)(row0 + wr) * 64 + (j >> 6)];
      float s = el_s[wr] + er[j];
      s = (s >= 0.f) ? s : 0.2f * s;
      s = ((wb >> (j & 63)) & 1ull) ? s : -9e15f;
      ws[wr][jj] = __expf(s - m_s[wr]);
    }
    __syncthreads();
#pragma unroll 16
    for (int jj = 0; jj < 64; jj++) {
      float wv = ws[r][jj];
      float4 h4 = *(const float4*)&hs[jj][c4];
      acc0 += wv * h4.x; acc1 += wv * h4.y; acc2 += wv * h4.z; acc3 += wv * h4.w;
    }
    __syncthreads();
  }

  // ---- epilogue: /Z, leaky 0.2, row L2-norm, +b, head-mean ----
  float invZ = 1.f / z_s[r];
  float v0 = acc0 * invZ, v1 = acc1 * invZ, v2 = acc2 * invZ, v3 = acc3 * invZ;
  v0 = (v0 >= 0.f) ? v0 : 0.2f * v0;
  v1 = (v1 >= 0.f) ? v1 : 0.2f * v1;
  v2 = (v2 >= 0.f) ? v2 : 0.2f * v2;
  v3 = (v3 >= 0.f) ? v3 : 0.2f * v3;
  float ss = v0 * v0 + v1 * v1 + v2 * v2 + v3 * v3;
#pragma unroll
  for (int off = 1; off < 32; off <<= 1) ss += __shfl_xor(ss, off, 64);
  float sc = 1.f / fmaxf(sqrtf(ss), 1e-12f);
  float4 bv = *(const float4*)&bvec[c4];
  float o0 = headw * (v0 * sc + bv.x);
  float o1 = headw * (v1 * sc + bv.y);
  float o2 = headw * (v2 * sc + bv.z);
  float o3 = headw * (v3 * sc + bv.w);
  float* op = out + (size_t)row * DH + c4;
  if (accum) {
    float4 cur = *(const float4*)op;
    float4 st = {cur.x + o0, cur.y + o1, cur.z + o2, cur.w + o3};
    *(float4*)op = st;
  } else {
    float4 st = {o0, o1, o2, o3};
    *(float4*)op = st;
  }
}

// ---------------- elementwise ELU ----------------
__global__ __launch_bounds__(256) void elu_k(const float* __restrict__ in, float* __restrict__ out, int n) {
  int i = blockIdx.x * 256 + threadIdx.x;
  if (i < n) {
    float v = in[i];
    out[i] = (v > 0.f) ? v : expm1f(v);
  }
}

// ---------------- gather tf/tg rows into GRU input ----------------
__global__ __launch_bounds__(256) void gather_k(const float* __restrict__ tf, const float* __restrict__ tg,
                                                const int* __restrict__ ts, float* __restrict__ hx_t) {
  int idx = blockIdx.x * 256 + threadIdx.x;   // NN*32
  int e = idx >> 5, c = idx & 31;
  int src = (c < 16) ? ts[e * 2] : ts[e * 2 + 1];
  float v = (c < 16) ? tf[(size_t)src * 16 + c] : tg[(size_t)src * 16 + (c - 16)];
  hx_t[idx] = v;
}

// ---------------- GRU gate fusion ----------------
__global__ __launch_bounds__(256) void gru_gate_k(const float* __restrict__ gi, const float* __restrict__ gh,
                                                  const float* __restrict__ hprev, float* __restrict__ hout) {
  int idx = blockIdx.x * 256 + threadIdx.x;   // NN*128
  int b = idx >> 7, c = idx & 127;
  const float* gib = gi + (size_t)b * 384;
  const float* ghb = gh + (size_t)b * 384;
  float ir = gib[c], iz = gib[128 + c], in_ = gib[256 + c];
  float hr = ghb[c], hz = ghb[128 + c], hn = ghb[256 + c];
  float rr = 1.f / (1.f + __expf(-(ir + hr)));
  float zz = 1.f / (1.f + __expf(-(iz + hz)));
  float nn_ = tanhf(in_ + rr * hn);
  hout[idx] = (1.f - zz) * nn_ + zz * hprev[idx];
}

// ---------------- temporal attention pooling ----------------
__global__ __launch_bounds__(256) void attpool_k(const float* __restrict__ z, const float* __restrict__ y,
                                                 float* __restrict__ o) {
  int idx = blockIdx.x * 256 + threadIdx.x;   // NN*128
  const size_t S = (size_t)NN * DH;
  float z0 = z[idx], z1 = z[idx + S], z2 = z[idx + 2 * S], z3 = z[idx + 3 * S];
  float mx = fmaxf(fmaxf(z0, z1), fmaxf(z2, z3));
  float e0 = __expf(z0 - mx), e1 = __expf(z1 - mx), e2 = __expf(z2 - mx), e3 = __expf(z3 - mx);
  float inv = 1.f / (e0 + e1 + e2 + e3);
  o[idx] = (e0 * y[idx] + e1 * y[idx + S] + e2 * y[idx + 2 * S] + e3 * y[idx + 3 * S]) * inv;
}

// ---------------- final projection: out = att_out @ fow + fob ----------------
__global__ __launch_bounds__(256) void final_k(const float* __restrict__ at, const float* __restrict__ fow,
                                               const float* __restrict__ fob, float* __restrict__ out) {
  int row = blockIdx.x * 4 + (threadIdx.x >> 6);
  int lane = threadIdx.x & 63;
  const float* ar = at + (size_t)row * DH;
  float p = ar[lane] * fow[lane] + ar[lane + 64] * fow[lane + 64];
#pragma unroll
  for (int off = 32; off >= 1; off >>= 1) p += __shfl_xor(p, off, 64);
  if (lane == 0) out[row] = p + fob[0];
}

// ---------------- host ----------------
static inline void run_gemm(int act, const float* A, const float* B, const float* bias, float* C,
                            int M, int N, int K, hipStream_t s) {
  dim3 g((N + 63) / 64, (M + 63) / 64), b(256);
  if (act == 0) gemm_k<0><<<g, b, 0, s>>>(A, B, bias, C, M, N, K);
  else          gemm_k<1><<<g, b, 0, s>>>(A, B, bias, C, M, N, K);
}

extern "C" void kernel_launch(void* const* d_in, const int* in_sizes, int n_in,
                              void* d_out, int out_size, void* d_ws, size_t ws_size,
                              hipStream_t stream) {
  const float* x[4]  = {(const float*)d_in[0], (const float*)d_in[1], (const float*)d_in[2], (const float*)d_in[3]};
  const int* adj     = (const int*)d_in[4];
  const int* tsample = (const int*)d_in[5];
  const float* nw[4] = {(const float*)d_in[6], (const float*)d_in[8], (const float*)d_in[10], (const float*)d_in[12]};
  const float* nb[4] = {(const float*)d_in[7], (const float*)d_in[9], (const float*)d_in[11], (const float*)d_in[13]};
  const float* W1 = (const float*)d_in[14];
  const float* a1 = (const float*)d_in[15];
  const float* b1 = (const float*)d_in[16];
  const float* W2 = (const float*)d_in[17];
  const float* a2 = (const float*)d_in[18];
  const float* b2 = (const float*)d_in[19];
  const float* tfw1 = (const float*)d_in[20]; const float* tfb1 = (const float*)d_in[21];
  const float* tfw2 = (const float*)d_in[22]; const float* tfb2 = (const float*)d_in[23];
  const float* tgw1 = (const float*)d_in[24]; const float* tgb1 = (const float*)d_in[25];
  const float* tgw2 = (const float*)d_in[26]; const float* tgb2 = (const float*)d_in[27];
  const float* wih0 = (const float*)d_in[28]; const float* whh0 = (const float*)d_in[29];
  const float* bih0 = (const float*)d_in[30]; const float* bhh0 = (const float*)d_in[31];
  const float* wih1 = (const float*)d_in[32]; const float* whh1 = (const float*)d_in[33];
  const float* bih1 = (const float*)d_in[34]; const float* bhh1 = (const float*)d_in[35];
  const float* attw = (const float*)d_in[36]; const float* attb = (const float*)d_in[37];
  const float* fow  = (const float*)d_in[38]; const float* fob  = (const float*)d_in[39];
  float* out = (float*)d_out;

  // workspace layout (bump allocator, 256B aligned)
  char* base = (char*)d_ws;
  size_t off = 0;
  auto alloc = [&](size_t bytes) -> void* {
    void* p = base + off;
    off += (bytes + 255) & ~(size_t)255;
    return p;
  };
  const size_t SN = (size_t)NN * DH;                  // 4096*128
  unsigned long long* mbits = (unsigned long long*)alloc((size_t)NN * 64 * 8);  // 2MB
  float* ebuf = (float*)alloc((size_t)NN * 256 * 4);  // 4MB  (reused as zbuf later)
  float* hbuf = (float*)alloc(SN * 4);                // 2MB  (reused as attout later)
  float* el   = (float*)alloc(NN * 4);
  float* er   = (float*)alloc(NN * 4);
  float* bufA = (float*)alloc(SN * 4);                // head-mean accumulator / embed
  float* bufB = (float*)alloc(SN * 4);                // elu output (layer-2 input)
  float* tmp1 = (float*)alloc((size_t)NN * 64 * 4);
  float* tfb_ = (float*)alloc((size_t)NN * 16 * 4);
  float* tgb_ = (float*)alloc((size_t)NN * 16 * 4);
  float* hx   = (float*)alloc((size_t)TP * NN * 32 * 4);  // 2MB
  float* y0   = (float*)alloc((size_t)TP * SN * 4);       // 8MB
  float* y1   = (float*)alloc((size_t)TP * SN * 4);       // 8MB
  float* gi   = (float*)alloc((size_t)NN * 384 * 4);      // 6MB
  float* gh   = (float*)alloc((size_t)NN * 384 * 4);      // 6MB
  float* zatt   = gi;     // 8MB needed; gi+gh contiguous 12MB, free after GRU
  float* zbuf   = ebuf;   // zeros for GRU h0; e free after timestep loop
  float* attout = hbuf;   // free after GAT

  const int TD[4] = {933, 303, 683, 798};

  // pack adjacency bitmask: 4096*64 words, 4 words/block
  pack_mask_k<<<(NN * 64) / 4, 256, 0, stream>>>(adj, mbits);

  for (int t = 0; t < TP; t++) {
    // e = x_t @ nw_t + nb_t        [4096 x 256]
    run_gemm(0, x[t], nw[t], nb[t], ebuf, NN, 256, TD[t], stream);
    // ---- GAT layer 1 (2 heads, mean) ----
    for (int hd = 0; hd < 2; hd++) {
      run_gemm(0, ebuf, W1 + (size_t)hd * 256 * DH, nullptr, hbuf, NN, DH, 256, stream);
      eler_k<<<NN / 4, 256, 0, stream>>>(hbuf, a1 + (size_t)hd * 256, el, er);
      gat_attn_k<<<NN / 8, 256, 0, stream>>>(hbuf, el, er, mbits, b1 + (size_t)hd * DH, bufA, 0.5f, hd);
    }
    elu_k<<<(int)(SN / 256), 256, 0, stream>>>(bufA, bufB, (int)SN);
    // ---- GAT layer 2 (2 heads, mean) ----
    for (int hd = 0; hd < 2; hd++) {
      run_gemm(0, bufB, W2 + (size_t)hd * DH * DH, nullptr, hbuf, NN, DH, DH, stream);
      eler_k<<<NN / 4, 256, 0, stream>>>(hbuf, a2 + (size_t)hd * 256, el, er);
      gat_attn_k<<<NN / 8, 256, 0, stream>>>(hbuf, el, er, mbits, b2 + (size_t)hd * DH, bufA, 0.5f, hd);
    }
    // ---- tf / tg MLPs (leaky 0.01) ----
    run_gemm(1, bufA, tfw1, tfb1, tmp1, NN, 64, DH, stream);
    run_gemm(1, tmp1, tfw2, tfb2, tfb_, NN, 16, 64, stream);
    run_gemm(1, bufA, tgw1, tgb1, tmp1, NN, 64, DH, stream);
    run_gemm(1, tmp1, tgw2, tgb2, tgb_, NN, 16, 64, stream);
    gather_k<<<(NN * 32) / 256, 256, 0, stream>>>(tfb_, tgb_, tsample, hx + (size_t)t * NN * 32);
  }

  // GRU h0 = zeros
  fill0_k<<<(int)(SN / 256), 256, 0, stream>>>(zbuf, (int)SN);

  // GRU layer 0: input 32 -> 128
  for (int t = 0; t < TP; t++) {
    const float* hprev = (t == 0) ? zbuf : (y0 + (size_t)(t - 1) * SN);
    run_gemm(0, hx + (size_t)t * NN * 32, wih0, bih0, gi, NN, 384, 32, stream);
    run_gemm(0, hprev, whh0, bhh0, gh, NN, 384, DH, stream);
    gru_gate_k<<<(int)(SN / 256), 256, 0, stream>>>(gi, gh, hprev, y0 + (size_t)t * SN);
  }
  // GRU layer 1: 128 -> 128
  for (int t = 0; t < TP; t++) {
    const float* hprev = (t == 0) ? zbuf : (y1 + (size_t)(t - 1) * SN);
    run_gemm(0, y0 + (size_t)t * SN, wih1, bih1, gi, NN, 384, DH, stream);
    run_gemm(0, hprev, whh1, bhh1, gh, NN, 384, DH, stream);
    gru_gate_k<<<(int)(SN / 256), 256, 0, stream>>>(gi, gh, hprev, y1 + (size_t)t * SN);
  }

  // temporal attention pooling
  for (int t = 0; t < TP; t++)
    run_gemm(0, y1 + (size_t)t * SN, attw, attb, zatt + (size_t)t * SN, NN, DH, DH, stream);
  attpool_k<<<(int)(SN / 256), 256, 0, stream>>>(zatt, y1, attout);
  final_k<<<NN / 4, 256, 0, stream>>>(attout, fow, fob, out);
}

// Round 2
// 2240.051 us; speedup vs baseline: 2.4421x; 2.4421x over previous
//
#include <hip/hip_runtime.h>
#include <cstdint>
#include <cstddef>

// ---------------- constants ----------------
#define NN 4096          // nodes
#define DH 128           // H1 == H2 == GRU_H
#define TP 4
#define ATT_S 4          // j-splits in attention
#define ATT_BM 64        // rows per attention block

typedef _Float16 f16x8 __attribute__((ext_vector_type(8)));
typedef float f32x4 __attribute__((ext_vector_type(4)));

// ---------------- pack adjacency into bitmask ----------------
__global__ __launch_bounds__(256) void pack_mask_k(const int* __restrict__ adj,
                                                   unsigned long long* __restrict__ mb) {
  int w = blockIdx.x * 4 + (threadIdx.x >> 6);
  int lane = threadIdx.x & 63;
  int v = adj[(size_t)w * 64 + lane];
  unsigned long long bits = __ballot(v > 0);
  if (lane == 0) mb[w] = bits;
}

// ---------------- zero fill ----------------
__global__ __launch_bounds__(256) void fill0_k(float* __restrict__ p, int n) {
  int i = blockIdx.x * 256 + threadIdx.x;
  if (i < n) p[i] = 0.f;
}

// ---------------- generic fp32 GEMM: C = act(A@B + bias) ----------------
template <int ACT>
__global__ __launch_bounds__(256) void gemm_k(const float* __restrict__ A, const float* __restrict__ B,
                                              const float* __restrict__ bias, float* __restrict__ C,
                                              int M, int N, int K) {
  __shared__ float As[16][72];
  __shared__ float Bs[16][64];
  const int tid = threadIdx.x;
  const int tx = tid & 15, ty = tid >> 4;
  const int bm = blockIdx.y * 64, bn = blockIdx.x * 64;
  const int kk = tid & 15, mbase = tid >> 4;
  const int nb = tid & 63, kb = tid >> 6;
  float acc[4][4] = {};
  for (int k0 = 0; k0 < K; k0 += 16) {
#pragma unroll
    for (int i = 0; i < 4; i++) {
      int m = mbase + i * 16;
      int gk = k0 + kk;
      As[kk][m] = (gk < K) ? A[(size_t)(bm + m) * K + gk] : 0.f;
    }
#pragma unroll
    for (int i = 0; i < 4; i++) {
      int kk2 = kb + i * 4;
      int gk = k0 + kk2;
      Bs[kk2][nb] = (gk < K && (bn + nb) < N) ? B[(size_t)gk * N + (bn + nb)] : 0.f;
    }
    __syncthreads();
#pragma unroll
    for (int k = 0; k < 16; k++) {
      float4 av = *(const float4*)&As[k][ty * 4];
      float4 bv = *(const float4*)&Bs[k][tx * 4];
      float a[4] = {av.x, av.y, av.z, av.w};
      float b[4] = {bv.x, bv.y, bv.z, bv.w};
#pragma unroll
      for (int i = 0; i < 4; i++)
#pragma unroll
        for (int j = 0; j < 4; j++) acc[i][j] += a[i] * b[j];
    }
    __syncthreads();
  }
  int cn = bn + tx * 4;
  if (cn + 3 < N) {
    float bv[4] = {0.f, 0.f, 0.f, 0.f};
    if (bias) {
      float4 t = *(const float4*)&bias[cn];
      bv[0] = t.x; bv[1] = t.y; bv[2] = t.z; bv[3] = t.w;
    }
#pragma unroll
    for (int i = 0; i < 4; i++) {
      int row = bm + ty * 4 + i;
      float o[4];
#pragma unroll
      for (int j = 0; j < 4; j++) {
        float v = acc[i][j] + bv[j];
        if (ACT == 1) v = (v >= 0.f) ? v : 0.01f * v;
        o[j] = v;
      }
      float4 st = {o[0], o[1], o[2], o[3]};
      *(float4*)&C[(size_t)row * N + cn] = st;
    }
  }
}

// ---------------- el/er: two dot products per row ----------------
__global__ __launch_bounds__(256) void eler_k(const float* __restrict__ h, const float* __restrict__ a,
                                              float* __restrict__ el, float* __restrict__ er) {
  int row = blockIdx.x * 4 + (threadIdx.x >> 6);
  int lane = threadIdx.x & 63;
  const float* hr = h + (size_t)row * DH;
  float h0 = hr[lane], h1 = hr[lane + 64];
  float pe = h0 * a[lane] + h1 * a[lane + 64];
  float pr = h0 * a[128 + lane] + h1 * a[192 + lane];
#pragma unroll
  for (int off = 32; off >= 1; off >>= 1) {
    pe += __shfl_xor(pe, off, 64);
    pr += __shfl_xor(pr, off, 64);
  }
  if (lane == 0) { el[row] = pe; er[row] = pr; }
}

// ---------------- exact masked row max: m = leaky(el + max_masked(er)) ----------------
// leaky is monotone increasing -> masked max of leaky(el_i + er_j) = leaky(el_i + max er_j)
__global__ __launch_bounds__(256) void rowmax_k(const float* __restrict__ el, const float* __restrict__ er,
                                                const unsigned long long* __restrict__ mb,
                                                float* __restrict__ mrow) {
  int head = blockIdx.y;
  int row = blockIdx.x * 4 + (threadIdx.x >> 6);
  int lane = threadIdx.x & 63;
  const float* erh = er + (size_t)head * NN;
  const unsigned long long* mr = mb + (size_t)row * 64;
  float mx = -INFINITY;
  for (int i = 0; i < 64; i++) {
    unsigned long long w = mr[i];
    float v = erh[i * 64 + lane];
    mx = fmaxf(mx, ((w >> lane) & 1ull) ? v : -INFINITY);
  }
#pragma unroll
  for (int off = 32; off >= 1; off >>= 1) mx = fmaxf(mx, __shfl_xor(mx, off, 64));
  if (lane == 0) {
    float s = el[(size_t)head * NN + row] + mx;
    mrow[(size_t)head * NN + row] = fmaxf(s, 0.2f * s);
  }
}

// ---------------- MFMA flash-GAT: accumulate O_part = P @ H, Z_part ----------------
// P = exp(leaky(el_i + er_j) - m_i) masked; f16 3-term split for ~fp32 accuracy.
// grid: (ATT_S, NN/ATT_BM, 2 heads), block 256 = 4 waves (2 in M x 2 in N).
__global__ __launch_bounds__(256) void gat_mfma_k(const float* __restrict__ h0p, const float* __restrict__ h1p,
                                                  const float* __restrict__ el, const float* __restrict__ er,
                                                  const float* __restrict__ mrow,
                                                  const unsigned long long* __restrict__ mb,
                                                  float* __restrict__ Opart, float* __restrict__ Zpart) {
  const int split = blockIdx.x;
  const int mblk = blockIdx.y;
  const int head = blockIdx.z;
  const float* h = head ? h1p : h0p;
  const float* elh = el + (size_t)head * NN;
  const float* erh = er + (size_t)head * NN;
  const float* mh = mrow + (size_t)head * NN;
  float* Op = Opart + ((size_t)head * ATT_S + split) * NN * DH;
  float* Zp = Zpart + ((size_t)head * ATT_S + split) * NN;

  __shared__ _Float16 PH[ATT_BM * 64];   // 8 KB, swizzled rows (128B stride)
  __shared__ _Float16 PL[ATT_BM * 64];   // 8 KB
  __shared__ _Float16 HH[128 * 64];      // 16 KB, H^T hi, swizzled
  __shared__ _Float16 HL[128 * 64];      // 16 KB, H^T lo
  __shared__ float zred[ATT_BM][4];

  const int tid = threadIdx.x;
  // P-compute mapping: 64 rows x 4 k-chunks of 16
  const int prow = tid >> 2;
  const int pk0 = (tid & 3) * 16;
  const int grow = mblk * ATT_BM + prow;
  const float el_r = elh[grow];
  const float m_r = mh[grow];
  // staging mapping: col 0..127, k-half 0..1
  const int sc = tid & 127;
  const int skh = tid >> 7;
  // wave mapping
  const int w = tid >> 6, lane = tid & 63;
  const int wm = w >> 1, wn = w & 1;
  const int l15 = lane & 15, l4 = lane >> 4;

  f32x4 acc[2][4] = {};   // [m2][nf]
  float zacc = 0.f;
  const int jbase = split * (NN / ATT_S);

  for (int jt = 0; jt < NN / ATT_S; jt += 64) {
    const int j0 = jbase + jt;
    __syncthreads();   // previous MFMA done reading LDS

    // ---- stage H^T tile (transpose + f16 hi/lo split) ----
#pragma unroll
    for (int kq = 0; kq < 4; kq++) {
      int k = skh * 32 + kq * 8;
      f16x8 hv, lv;
#pragma unroll
      for (int e = 0; e < 8; e++) {
        float v = h[(size_t)(j0 + k + e) * DH + sc];
        _Float16 hi = (_Float16)v;
        hv[e] = hi;
        lv[e] = (_Float16)(v - (float)hi);
      }
      int byt = ((sc * 64 + k) * 2) ^ ((sc & 7) << 4);
      *(f16x8*)((char*)HH + byt) = hv;
      *(f16x8*)((char*)HL + byt) = lv;
    }

    // ---- compute P tile (64 x 64), f16 hi/lo, swizzled row-major ----
    {
      unsigned long long wbits = mb[(size_t)grow * 64 + (j0 >> 6)];
      float er_v[16];
#pragma unroll
      for (int q = 0; q < 4; q++) {
        float4 t = *(const float4*)&erh[j0 + pk0 + q * 4];
        er_v[q * 4 + 0] = t.x; er_v[q * 4 + 1] = t.y;
        er_v[q * 4 + 2] = t.z; er_v[q * 4 + 3] = t.w;
      }
      f16x8 hv[2], lv[2];
#pragma unroll
      for (int e = 0; e < 16; e++) {
        float sr = el_r + er_v[e];
        float s = fmaxf(sr, 0.2f * sr);                       // leaky 0.2
        float p = ((wbits >> (pk0 + e)) & 1ull) ? __expf(s - m_r) : 0.f;
        zacc += p;
        _Float16 hi = (_Float16)p;
        hv[e >> 3][e & 7] = hi;
        lv[e >> 3][e & 7] = (_Float16)(p - (float)hi);
      }
#pragma unroll
      for (int half = 0; half < 2; half++) {
        int byt = (((prow * 64) + pk0 + half * 8) * 2) ^ ((prow & 7) << 4);
        *(f16x8*)((char*)PH + byt) = hv[half];
        *(f16x8*)((char*)PL + byt) = lv[half];
      }
    }
    __syncthreads();   // LDS tiles ready

    // ---- MFMA: acc += Phi*Hhi + Phi*Hlo + Plo*Hhi ----
#pragma unroll
    for (int kf = 0; kf < 2; kf++) {
      f16x8 ah[2], al[2];
#pragma unroll
      for (int m2 = 0; m2 < 2; m2++) {
        int ar = wm * 32 + m2 * 16 + l15;
        int ak = kf * 32 + l4 * 8;
        int ab = ((ar * 64 + ak) * 2) ^ ((ar & 7) << 4);
        ah[m2] = *(const f16x8*)((const char*)PH + ab);
        al[m2] = *(const f16x8*)((const char*)PL + ab);
      }
#pragma unroll
      for (int nf = 0; nf < 4; nf++) {
        int bc = wn * 64 + nf * 16 + l15;
        int bk = kf * 32 + l4 * 8;
        int bb = ((bc * 64 + bk) * 2) ^ ((bc & 7) << 4);
        f16x8 bh = *(const f16x8*)((const char*)HH + bb);
        f16x8 bl = *(const f16x8*)((const char*)HL + bb);
#pragma unroll
        for (int m2 = 0; m2 < 2; m2++) {
          acc[m2][nf] = __builtin_amdgcn_mfma_f32_16x16x32_f16(ah[m2], bh, acc[m2][nf], 0, 0, 0);
          acc[m2][nf] = __builtin_amdgcn_mfma_f32_16x16x32_f16(ah[m2], bl, acc[m2][nf], 0, 0, 0);
          acc[m2][nf] = __builtin_amdgcn_mfma_f32_16x16x32_f16(al[m2], bh, acc[m2][nf], 0, 0, 0);
        }
      }
    }
  }

  // ---- Z reduce ----
  zred[prow][tid & 3] = zacc;
  __syncthreads();
  if (tid < ATT_BM) {
    float z = zred[tid][0] + zred[tid][1] + zred[tid][2] + zred[tid][3];
    Zp[mblk * ATT_BM + tid] = z;
  }

  // ---- O_part store (C/D layout: col = lane&15, row = (lane>>4)*4 + reg) ----
#pragma unroll
  for (int m2 = 0; m2 < 2; m2++)
#pragma unroll
    for (int nf = 0; nf < 4; nf++)
#pragma unroll
      for (int q = 0; q < 4; q++) {
        int r = mblk * ATT_BM + wm * 32 + m2 * 16 + l4 * 4 + q;
        int c = wn * 64 + nf * 16 + l15;
        Op[(size_t)r * DH + c] = acc[m2][nf][q];
      }
}

// ---------------- combine partials -> head mean (+optional ELU) ----------------
template <int DO_ELU>
__global__ __launch_bounds__(256) void combine_k(const float* __restrict__ Opart,
                                                 const float* __restrict__ Zpart,
                                                 const float* __restrict__ bvec,
                                                 float* __restrict__ out) {
  int row = blockIdx.x * 4 + (threadIdx.x >> 6);
  int lane = threadIdx.x & 63;
  int c = lane * 2;
  float o0 = 0.f, o1 = 0.f;
#pragma unroll
  for (int hd = 0; hd < 2; hd++) {
    float a0 = 0.f, a1 = 0.f, Z = 0.f;
#pragma unroll
    for (int s = 0; s < ATT_S; s++) {
      const float* Op = Opart + ((size_t)hd * ATT_S + s) * NN * DH;
      float2 t = *(const float2*)&Op[(size_t)row * DH + c];
      a0 += t.x; a1 += t.y;
      Z += Zpart[((size_t)hd * ATT_S + s) * NN + row];
    }
    float invZ = 1.f / Z;
    float v0 = a0 * invZ, v1 = a1 * invZ;
    v0 = fmaxf(v0, 0.2f * v0);
    v1 = fmaxf(v1, 0.2f * v1);
    float ss = v0 * v0 + v1 * v1;
#pragma unroll
    for (int off = 32; off >= 1; off >>= 1) ss += __shfl_xor(ss, off, 64);
    float sc_ = 1.f / fmaxf(sqrtf(ss), 1e-12f);
    o0 += 0.5f * (v0 * sc_ + bvec[hd * DH + c]);
    o1 += 0.5f * (v1 * sc_ + bvec[hd * DH + c + 1]);
  }
  if (DO_ELU) {
    o0 = (o0 > 0.f) ? o0 : expm1f(o0);
    o1 = (o1 > 0.f) ? o1 : expm1f(o1);
  }
  float2 st = {o0, o1};
  *(float2*)&out[(size_t)row * DH + c] = st;
}

// ---------------- gather tf/tg rows into GRU input ----------------
__global__ __launch_bounds__(256) void gather_k(const float* __restrict__ tf, const float* __restrict__ tg,
                                                const int* __restrict__ ts, float* __restrict__ hx_t) {
  int idx = blockIdx.x * 256 + threadIdx.x;
  int e = idx >> 5, c = idx & 31;
  int src = (c < 16) ? ts[e * 2] : ts[e * 2 + 1];
  float v = (c < 16) ? tf[(size_t)src * 16 + c] : tg[(size_t)src * 16 + (c - 16)];
  hx_t[idx] = v;
}

// ---------------- GRU gate fusion ----------------
__global__ __launch_bounds__(256) void gru_gate_k(const float* __restrict__ gi, const float* __restrict__ gh,
                                                  const float* __restrict__ hprev, float* __restrict__ hout) {
  int idx = blockIdx.x * 256 + threadIdx.x;
  int b = idx >> 7, c = idx & 127;
  const float* gib = gi + (size_t)b * 384;
  const float* ghb = gh + (size_t)b * 384;
  float ir = gib[c], iz = gib[128 + c], in_ = gib[256 + c];
  float hr = ghb[c], hz = ghb[128 + c], hn = ghb[256 + c];
  float rr = 1.f / (1.f + __expf(-(ir + hr)));
  float zz = 1.f / (1.f + __expf(-(iz + hz)));
  float nn_ = tanhf(in_ + rr * hn);
  hout[idx] = (1.f - zz) * nn_ + zz * hprev[idx];
}

// ---------------- temporal attention pooling ----------------
__global__ __launch_bounds__(256) void attpool_k(const float* __restrict__ z, const float* __restrict__ y,
                                                 float* __restrict__ o) {
  int idx = blockIdx.x * 256 + threadIdx.x;
  const size_t S = (size_t)NN * DH;
  float z0 = z[idx], z1 = z[idx + S], z2 = z[idx + 2 * S], z3 = z[idx + 3 * S];
  float mx = fmaxf(fmaxf(z0, z1), fmaxf(z2, z3));
  float e0 = __expf(z0 - mx), e1 = __expf(z1 - mx), e2 = __expf(z2 - mx), e3 = __expf(z3 - mx);
  float inv = 1.f / (e0 + e1 + e2 + e3);
  o[idx] = (e0 * y[idx] + e1 * y[idx + S] + e2 * y[idx + 2 * S] + e3 * y[idx + 3 * S]) * inv;
}

// ---------------- final projection ----------------
__global__ __launch_bounds__(256) void final_k(const float* __restrict__ at, const float* __restrict__ fow,
                                               const float* __restrict__ fob, float* __restrict__ out) {
  int row = blockIdx.x * 4 + (threadIdx.x >> 6);
  int lane = threadIdx.x & 63;
  const float* ar = at + (size_t)row * DH;
  float p = ar[lane] * fow[lane] + ar[lane + 64] * fow[lane + 64];
#pragma unroll
  for (int off = 32; off >= 1; off >>= 1) p += __shfl_xor(p, off, 64);
  if (lane == 0) out[row] = p + fob[0];
}

// ---------------- host ----------------
static inline void run_gemm(int act, const float* A, const float* B, const float* bias, float* C,
                            int M, int N, int K, hipStream_t s) {
  dim3 g((N + 63) / 64, (M + 63) / 64), b(256);
  if (act == 0) gemm_k<0><<<g, b, 0, s>>>(A, B, bias, C, M, N, K);
  else          gemm_k<1><<<g, b, 0, s>>>(A, B, bias, C, M, N, K);
}

extern "C" void kernel_launch(void* const* d_in, const int* in_sizes, int n_in,
                              void* d_out, int out_size, void* d_ws, size_t ws_size,
                              hipStream_t stream) {
  const float* x[4]  = {(const float*)d_in[0], (const float*)d_in[1], (const float*)d_in[2], (const float*)d_in[3]};
  const int* adj     = (const int*)d_in[4];
  const int* tsample = (const int*)d_in[5];
  const float* nw[4] = {(const float*)d_in[6], (const float*)d_in[8], (const float*)d_in[10], (const float*)d_in[12]};
  const float* nb[4] = {(const float*)d_in[7], (const float*)d_in[9], (const float*)d_in[11], (const float*)d_in[13]};
  const float* W1 = (const float*)d_in[14];
  const float* a1 = (const float*)d_in[15];
  const float* b1 = (const float*)d_in[16];
  const float* W2 = (const float*)d_in[17];
  const float* a2 = (const float*)d_in[18];
  const float* b2 = (const float*)d_in[19];
  const float* tfw1 = (const float*)d_in[20]; const float* tfb1 = (const float*)d_in[21];
  const float* tfw2 = (const float*)d_in[22]; const float* tfb2 = (const float*)d_in[23];
  const float* tgw1 = (const float*)d_in[24]; const float* tgb1 = (const float*)d_in[25];
  const float* tgw2 = (const float*)d_in[26]; const float* tgb2 = (const float*)d_in[27];
  const float* wih0 = (const float*)d_in[28]; const float* whh0 = (const float*)d_in[29];
  const float* bih0 = (const float*)d_in[30]; const float* bhh0 = (const float*)d_in[31];
  const float* wih1 = (const float*)d_in[32]; const float* whh1 = (const float*)d_in[33];
  const float* bih1 = (const float*)d_in[34]; const float* bhh1 = (const float*)d_in[35];
  const float* attw = (const float*)d_in[36]; const float* attb = (const float*)d_in[37];
  const float* fow  = (const float*)d_in[38]; const float* fob  = (const float*)d_in[39];
  float* out = (float*)d_out;

  // workspace layout (bump allocator, 256B aligned)
  char* base = (char*)d_ws;
  size_t off = 0;
  auto alloc = [&](size_t bytes) -> void* {
    void* p = base + off;
    off += (bytes + 255) & ~(size_t)255;
    return p;
  };
  const size_t SN = (size_t)NN * DH;
  unsigned long long* mbits = (unsigned long long*)alloc((size_t)NN * 64 * 8);  // 2MB
  float* ebuf = (float*)alloc((size_t)NN * 256 * 4);  // 4MB  (reused as zbuf later)
  float* h0   = (float*)alloc(SN * 4);                // 2MB  head-0 h; reused as attout
  float* h1   = (float*)alloc(SN * 4);                // 2MB  head-1 h
  float* el   = (float*)alloc((size_t)2 * NN * 4);
  float* er   = (float*)alloc((size_t)2 * NN * 4);
  float* mrowb= (float*)alloc((size_t)2 * NN * 4);
  float* bufA = (float*)alloc(SN * 4);                // layer-2 output (embed)
  float* bufB = (float*)alloc(SN * 4);                // layer-1 output after ELU
  float* tmp1 = (float*)alloc((size_t)NN * 64 * 4);
  float* tfb_ = (float*)alloc((size_t)NN * 16 * 4);
  float* tgb_ = (float*)alloc((size_t)NN * 16 * 4);
  float* hx   = (float*)alloc((size_t)TP * NN * 32 * 4);  // 2MB
  float* y0   = (float*)alloc((size_t)TP * SN * 4);       // 8MB  } Opart aliases
  float* y1   = (float*)alloc((size_t)TP * SN * 4);       // 8MB  } y0+y1 (16MB, pre-GRU)
  float* gi   = (float*)alloc((size_t)NN * 384 * 4);      // 6MB  } Zpart aliases gi
  float* gh   = (float*)alloc((size_t)NN * 384 * 4);      // 6MB
  float* Opart = y0;       // [2][ATT_S][NN][DH] fp32 = 16MB, dead before GRU writes y0/y1
  float* Zpart = gi;       // [2][ATT_S][NN] = 128KB, dead before GRU writes gi
  float* zatt   = gi;      // pooling scratch (post-GRU)
  float* zbuf   = ebuf;    // GRU h0 zeros
  float* attout = h0;      // pooled output

  const int TD[4] = {933, 303, 683, 798};

  pack_mask_k<<<(NN * 64) / 4, 256, 0, stream>>>(adj, mbits);

  for (int t = 0; t < TP; t++) {
    // e = x_t @ nw_t + nb_t    [4096 x 256]
    run_gemm(0, x[t], nw[t], nb[t], ebuf, NN, 256, TD[t], stream);

    // ---- GAT layer 1 (2 heads, mean, +ELU) ----
    for (int hd = 0; hd < 2; hd++) {
      float* hp = hd ? h1 : h0;
      run_gemm(0, ebuf, W1 + (size_t)hd * 256 * DH, nullptr, hp, NN, DH, 256, stream);
      eler_k<<<NN / 4, 256, 0, stream>>>(hp, a1 + (size_t)hd * 256, el + (size_t)hd * NN, er + (size_t)hd * NN);
    }
    rowmax_k<<<dim3(NN / 4, 2), 256, 0, stream>>>(el, er, mbits, mrowb);
    gat_mfma_k<<<dim3(ATT_S, NN / ATT_BM, 2), 256, 0, stream>>>(h0, h1, el, er, mrowb, mbits, Opart, Zpart);
    combine_k<1><<<NN / 4, 256, 0, stream>>>(Opart, Zpart, b1, bufB);

    // ---- GAT layer 2 (2 heads, mean) ----
    for (int hd = 0; hd < 2; hd++) {
      float* hp = hd ? h1 : h0;
      run_gemm(0, bufB, W2 + (size_t)hd * DH * DH, nullptr, hp, NN, DH, DH, stream);
      eler_k<<<NN / 4, 256, 0, stream>>>(hp, a2 + (size_t)hd * 256, el + (size_t)hd * NN, er + (size_t)hd * NN);
    }
    rowmax_k<<<dim3(NN / 4, 2), 256, 0, stream>>>(el, er, mbits, mrowb);
    gat_mfma_k<<<dim3(ATT_S, NN / ATT_BM, 2), 256, 0, stream>>>(h0, h1, el, er, mrowb, mbits, Opart, Zpart);
    combine_k<0><<<NN / 4, 256, 0, stream>>>(Opart, Zpart, b2, bufA);

    // ---- tf / tg MLPs (leaky 0.01) ----
    run_gemm(1, bufA, tfw1, tfb1, tmp1, NN, 64, DH, stream);
    run_gemm(1, tmp1, tfw2, tfb2, tfb_, NN, 16, 64, stream);
    run_gemm(1, bufA, tgw1, tgb1, tmp1, NN, 64, DH, stream);
    run_gemm(1, tmp1, tgw2, tgb2, tgb_, NN, 16, 64, stream);
    gather_k<<<(NN * 32) / 256, 256, 0, stream>>>(tfb_, tgb_, tsample, hx + (size_t)t * NN * 32);
  }

  // GRU h0 = zeros
  fill0_k<<<(int)(SN / 256), 256, 0, stream>>>(zbuf, (int)SN);

  // GRU layer 0: input 32 -> 128
  for (int t = 0; t < TP; t++) {
    const float* hprev = (t == 0) ? zbuf : (y0 + (size_t)(t - 1) * SN);
    run_gemm(0, hx + (size_t)t * NN * 32, wih0, bih0, gi, NN, 384, 32, stream);
    run_gemm(0, hprev, whh0, bhh0, gh, NN, 384, DH, stream);
    gru_gate_k<<<(int)(SN / 256), 256, 0, stream>>>(gi, gh, hprev, y0 + (size_t)t * SN);
  }
  // GRU layer 1: 128 -> 128
  for (int t = 0; t < TP; t++) {
    const float* hprev = (t == 0) ? zbuf : (y1 + (size_t)(t - 1) * SN);
    run_gemm(0, y0 + (size_t)t * SN, wih1, bih1, gi, NN, 384, DH, stream);
    run_gemm(0, hprev, whh1, bhh1, gh, NN, 384, DH, stream);
    gru_gate_k<<<(int)(SN / 256), 256, 0, stream>>>(gi, gh, hprev, y1 + (size_t)t * SN);
  }

  // temporal attention pooling
  for (int t = 0; t < TP; t++)
    run_gemm(0, y1 + (size_t)t * SN, attw, attb, zatt + (size_t)t * SN, NN, DH, DH, stream);
  attpool_k<<<(int)(SN / 256), 256, 0, stream>>>(zatt, y1, attout);
  final_k<<<NN / 4, 256, 0, stream>>>(attout, fow, fob, out);
}

// Round 5
// 1556.193 us; speedup vs baseline: 3.5152x; 1.4394x over previous
//
#include <hip/hip_runtime.h>
#include <cstdint>
#include <cstddef>

// ---------------- constants ----------------
#define NN 4096          // nodes
#define DH 128           // H1 == H2 == GRU_H
#define TP 4
#define ATT_S 4          // j-splits in attention
#define ATT_BM 64        // rows per attention block

typedef _Float16 f16x8 __attribute__((ext_vector_type(8)));
typedef float f32x4 __attribute__((ext_vector_type(4)));

// ---------------- pack adjacency into bitmask ----------------
__global__ __launch_bounds__(256) void pack_mask_k(const int* __restrict__ adj,
                                                   unsigned long long* __restrict__ mb) {
  int w = blockIdx.x * 4 + (threadIdx.x >> 6);
  int lane = threadIdx.x & 63;
  int v = adj[(size_t)w * 64 + lane];
  unsigned long long bits = __ballot(v > 0);
  if (lane == 0) mb[w] = bits;
}

// ---------------- zero fill ----------------
__global__ __launch_bounds__(256) void fill0_k(float* __restrict__ p, int n) {
  int i = blockIdx.x * 256 + threadIdx.x;
  if (i < n) p[i] = 0.f;
}

// ---------------- MFMA fp32-via-f16-split GEMM: C = act(A@B + bias) ----------------
// 64x64 tile, BK=64, 4 waves (2x2), each wave a 32x32 quadrant.
// a = a_hi + a_lo (f16 split); a@b ~= ah@bh + ah@bl + al@bh  (~2^-22 rel err).
// M must be a multiple of 64; N,K arbitrary (zero-padded in LDS, bounds on store).
template <int ACT>
__global__ __launch_bounds__(256) void gemm_mfma_k(const float* __restrict__ A, const float* __restrict__ B,
                                                   const float* __restrict__ bias, float* __restrict__ C,
                                                   int M, int N, int K) {
  __shared__ _Float16 AH[64 * 64], AL[64 * 64];   // 8KB each, swizzled rows (128B stride)
  __shared__ _Float16 BH[64 * 64], BL[64 * 64];   // B^T tiles [col][k]
  const int tid = threadIdx.x;
  const int bm = blockIdx.y * 64, bn = blockIdx.x * 64;
  const int arow = tid >> 2, akc = (tid & 3) * 16;     // A staging
  const int bcol = tid & 63, bkc = (tid >> 6) * 16;    // B staging
  const int w = tid >> 6, lane = tid & 63;
  const int wm = w >> 1, wn = w & 1;
  const int l15 = lane & 15, l4 = lane >> 4;
  f32x4 acc[2][2] = {};

  for (int k0 = 0; k0 < K; k0 += 64) {
    __syncthreads();
    // ---- stage A tile (f16 hi/lo split, swizzled) ----
    {
      const float* ar = A + (size_t)(bm + arow) * K;
      f16x8 hv[2], lv[2];
#pragma unroll
      for (int e = 0; e < 16; e++) {
        int gk = k0 + akc + e;
        float v = (gk < K) ? ar[gk] : 0.f;
        _Float16 hi = (_Float16)v;
        hv[e >> 3][e & 7] = hi;
        lv[e >> 3][e & 7] = (_Float16)(v - (float)hi);
      }
#pragma unroll
      for (int hf = 0; hf < 2; hf++) {
        int byt = ((arow * 64 + akc + hf * 8) * 2) ^ ((arow & 7) << 4);
        *(f16x8*)((char*)AH + byt) = hv[hf];
        *(f16x8*)((char*)AL + byt) = lv[hf];
      }
    }
    // ---- stage B^T tile ----
    {
      f16x8 hv[2], lv[2];
      const bool cok = (bn + bcol) < N;
#pragma unroll
      for (int e = 0; e < 16; e++) {
        int gk = k0 + bkc + e;
        float v = (gk < K && cok) ? B[(size_t)gk * N + bn + bcol] : 0.f;
        _Float16 hi = (_Float16)v;
        hv[e >> 3][e & 7] = hi;
        lv[e >> 3][e & 7] = (_Float16)(v - (float)hi);
      }
#pragma unroll
      for (int hf = 0; hf < 2; hf++) {
        int byt = ((bcol * 64 + bkc + hf * 8) * 2) ^ ((bcol & 7) << 4);
        *(f16x8*)((char*)BH + byt) = hv[hf];
        *(f16x8*)((char*)BL + byt) = lv[hf];
      }
    }
    __syncthreads();
    // ---- MFMA ----
#pragma unroll
    for (int kf = 0; kf < 2; kf++) {
      f16x8 ah[2], al[2], bh[2], bl[2];
#pragma unroll
      for (int m2 = 0; m2 < 2; m2++) {
        int r = wm * 32 + m2 * 16 + l15;
        int byt = ((r * 64 + kf * 32 + l4 * 8) * 2) ^ ((r & 7) << 4);
        ah[m2] = *(const f16x8*)((const char*)AH + byt);
        al[m2] = *(const f16x8*)((const char*)AL + byt);
      }
#pragma unroll
      for (int nf = 0; nf < 2; nf++) {
        int c = wn * 32 + nf * 16 + l15;
        int byt = ((c * 64 + kf * 32 + l4 * 8) * 2) ^ ((c & 7) << 4);
        bh[nf] = *(const f16x8*)((const char*)BH + byt);
        bl[nf] = *(const f16x8*)((const char*)BL + byt);
      }
#pragma unroll
      for (int m2 = 0; m2 < 2; m2++)
#pragma unroll
        for (int nf = 0; nf < 2; nf++) {
          acc[m2][nf] = __builtin_amdgcn_mfma_f32_16x16x32_f16(ah[m2], bh[nf], acc[m2][nf], 0, 0, 0);
          acc[m2][nf] = __builtin_amdgcn_mfma_f32_16x16x32_f16(ah[m2], bl[nf], acc[m2][nf], 0, 0, 0);
          acc[m2][nf] = __builtin_amdgcn_mfma_f32_16x16x32_f16(al[m2], bh[nf], acc[m2][nf], 0, 0, 0);
        }
    }
  }
  // ---- epilogue (C/D layout: col=lane&15, row=(lane>>4)*4+q) ----
#pragma unroll
  for (int m2 = 0; m2 < 2; m2++)
#pragma unroll
    for (int nf = 0; nf < 2; nf++) {
      int c = bn + wn * 32 + nf * 16 + l15;
      if (c < N) {
        float bv = bias ? bias[c] : 0.f;
#pragma unroll
        for (int q = 0; q < 4; q++) {
          int r = bm + wm * 32 + m2 * 16 + l4 * 4 + q;
          float v = acc[m2][nf][q] + bv;
          if (ACT == 1) v = (v >= 0.f) ? v : 0.01f * v;
          C[(size_t)r * N + c] = v;
        }
      }
    }
}

// ---------------- el/er for both heads ----------------
__global__ __launch_bounds__(256) void eler_k(const float* __restrict__ h0p, const float* __restrict__ h1p,
                                              const float* __restrict__ a,
                                              float* __restrict__ el, float* __restrict__ er) {
  int head = blockIdx.y;
  const float* h = head ? h1p : h0p;
  const float* ah = a + (size_t)head * 256;
  int row = blockIdx.x * 4 + (threadIdx.x >> 6);
  int lane = threadIdx.x & 63;
  const float* hr = h + (size_t)row * DH;
  float h0 = hr[lane], h1 = hr[lane + 64];
  float pe = h0 * ah[lane] + h1 * ah[lane + 64];
  float pr = h0 * ah[128 + lane] + h1 * ah[192 + lane];
#pragma unroll
  for (int off = 32; off >= 1; off >>= 1) {
    pe += __shfl_xor(pe, off, 64);
    pr += __shfl_xor(pr, off, 64);
  }
  if (lane == 0) { el[(size_t)head * NN + row] = pe; er[(size_t)head * NN + row] = pr; }
}

// ---------------- exact masked row max: m = leaky(el + max_masked(er)) ----------------
__global__ __launch_bounds__(256) void rowmax_k(const float* __restrict__ el, const float* __restrict__ er,
                                                const unsigned long long* __restrict__ mb,
                                                float* __restrict__ mrow) {
  int head = blockIdx.y;
  int row = blockIdx.x * 4 + (threadIdx.x >> 6);
  int lane = threadIdx.x & 63;
  const float* erh = er + (size_t)head * NN;
  const unsigned long long* mr = mb + (size_t)row * 64;
  float mx = -INFINITY;
  for (int i = 0; i < 64; i++) {
    unsigned long long w = mr[i];
    float v = erh[i * 64 + lane];
    mx = fmaxf(mx, ((w >> lane) & 1ull) ? v : -INFINITY);
  }
#pragma unroll
  for (int off = 32; off >= 1; off >>= 1) mx = fmaxf(mx, __shfl_xor(mx, off, 64));
  if (lane == 0) {
    float s = el[(size_t)head * NN + row] + mx;
    mrow[(size_t)head * NN + row] = fmaxf(s, 0.2f * s);
  }
}

// ---------------- MFMA flash-GAT: accumulate O_part = P @ H, Z_part ----------------
__global__ __launch_bounds__(256) void gat_mfma_k(const float* __restrict__ h0p, const float* __restrict__ h1p,
                                                  const float* __restrict__ el, const float* __restrict__ er,
                                                  const float* __restrict__ mrow,
                                                  const unsigned long long* __restrict__ mb,
                                                  float* __restrict__ Opart, float* __restrict__ Zpart) {
  const int split = blockIdx.x;
  const int mblk = blockIdx.y;
  const int head = blockIdx.z;
  const float* h = head ? h1p : h0p;
  const float* elh = el + (size_t)head * NN;
  const float* erh = er + (size_t)head * NN;
  const float* mh = mrow + (size_t)head * NN;
  float* Op = Opart + ((size_t)head * ATT_S + split) * NN * DH;
  float* Zp = Zpart + ((size_t)head * ATT_S + split) * NN;

  __shared__ _Float16 PH[ATT_BM * 64];   // 8 KB
  __shared__ _Float16 PL[ATT_BM * 64];   // 8 KB
  __shared__ _Float16 HH[128 * 64];      // 16 KB, H^T hi
  __shared__ _Float16 HL[128 * 64];      // 16 KB
  __shared__ float zred[ATT_BM][4];

  const int tid = threadIdx.x;
  const int prow = tid >> 2;
  const int pk0 = (tid & 3) * 16;
  const int grow = mblk * ATT_BM + prow;
  const float el_r = elh[grow];
  const float m_r = mh[grow];
  const int sc = tid & 127;
  const int skh = tid >> 7;
  const int w = tid >> 6, lane = tid & 63;
  const int wm = w >> 1, wn = w & 1;
  const int l15 = lane & 15, l4 = lane >> 4;

  f32x4 acc[2][4] = {};
  float zacc = 0.f;
  const int jbase = split * (NN / ATT_S);

  for (int jt = 0; jt < NN / ATT_S; jt += 64) {
    const int j0 = jbase + jt;
    __syncthreads();

    // ---- stage H^T tile ----
#pragma unroll
    for (int kq = 0; kq < 4; kq++) {
      int k = skh * 32 + kq * 8;
      f16x8 hv, lv;
#pragma unroll
      for (int e = 0; e < 8; e++) {
        float v = h[(size_t)(j0 + k + e) * DH + sc];
        _Float16 hi = (_Float16)v;
        hv[e] = hi;
        lv[e] = (_Float16)(v - (float)hi);
      }
      int byt = ((sc * 64 + k) * 2) ^ ((sc & 7) << 4);
      *(f16x8*)((char*)HH + byt) = hv;
      *(f16x8*)((char*)HL + byt) = lv;
    }

    // ---- compute P tile ----
    {
      unsigned long long wbits = mb[(size_t)grow * 64 + (j0 >> 6)];
      float er_v[16];
#pragma unroll
      for (int q = 0; q < 4; q++) {
        float4 t = *(const float4*)&erh[j0 + pk0 + q * 4];
        er_v[q * 4 + 0] = t.x; er_v[q * 4 + 1] = t.y;
        er_v[q * 4 + 2] = t.z; er_v[q * 4 + 3] = t.w;
      }
      f16x8 hv[2], lv[2];
#pragma unroll
      for (int e = 0; e < 16; e++) {
        float sr = el_r + er_v[e];
        float s = fmaxf(sr, 0.2f * sr);
        float p = ((wbits >> (pk0 + e)) & 1ull) ? __expf(s - m_r) : 0.f;
        zacc += p;
        _Float16 hi = (_Float16)p;
        hv[e >> 3][e & 7] = hi;
        lv[e >> 3][e & 7] = (_Float16)(p - (float)hi);
      }
#pragma unroll
      for (int half = 0; half < 2; half++) {
        int byt = (((prow * 64) + pk0 + half * 8) * 2) ^ ((prow & 7) << 4);
        *(f16x8*)((char*)PH + byt) = hv[half];
        *(f16x8*)((char*)PL + byt) = lv[half];
      }
    }
    __syncthreads();

    // ---- MFMA ----
#pragma unroll
    for (int kf = 0; kf < 2; kf++) {
      f16x8 ah[2], al[2];
#pragma unroll
      for (int m2 = 0; m2 < 2; m2++) {
        int ar = wm * 32 + m2 * 16 + l15;
        int ak = kf * 32 + l4 * 8;
        int ab = ((ar * 64 + ak) * 2) ^ ((ar & 7) << 4);
        ah[m2] = *(const f16x8*)((const char*)PH + ab);
        al[m2] = *(const f16x8*)((const char*)PL + ab);
      }
#pragma unroll
      for (int nf = 0; nf < 4; nf++) {
        int bc = wn * 64 + nf * 16 + l15;
        int bk = kf * 32 + l4 * 8;
        int bb = ((bc * 64 + bk) * 2) ^ ((bc & 7) << 4);
        f16x8 bh = *(const f16x8*)((const char*)HH + bb);
        f16x8 bl = *(const f16x8*)((const char*)HL + bb);
#pragma unroll
        for (int m2 = 0; m2 < 2; m2++) {
          acc[m2][nf] = __builtin_amdgcn_mfma_f32_16x16x32_f16(ah[m2], bh, acc[m2][nf], 0, 0, 0);
          acc[m2][nf] = __builtin_amdgcn_mfma_f32_16x16x32_f16(ah[m2], bl, acc[m2][nf], 0, 0, 0);
          acc[m2][nf] = __builtin_amdgcn_mfma_f32_16x16x32_f16(al[m2], bh, acc[m2][nf], 0, 0, 0);
        }
      }
    }
  }

  // ---- Z reduce ----
  zred[prow][tid & 3] = zacc;
  __syncthreads();
  if (tid < ATT_BM) {
    float z = zred[tid][0] + zred[tid][1] + zred[tid][2] + zred[tid][3];
    Zp[mblk * ATT_BM + tid] = z;
  }

  // ---- O_part store ----
#pragma unroll
  for (int m2 = 0; m2 < 2; m2++)
#pragma unroll
    for (int nf = 0; nf < 4; nf++)
#pragma unroll
      for (int q = 0; q < 4; q++) {
        int r = mblk * ATT_BM + wm * 32 + m2 * 16 + l4 * 4 + q;
        int c = wn * 64 + nf * 16 + l15;
        Op[(size_t)r * DH + c] = acc[m2][nf][q];
      }
}

// ---------------- combine partials -> head mean (+optional ELU) ----------------
template <int DO_ELU>
__global__ __launch_bounds__(256) void combine_k(const float* __restrict__ Opart,
                                                 const float* __restrict__ Zpart,
                                                 const float* __restrict__ bvec,
                                                 float* __restrict__ out) {
  int row = blockIdx.x * 4 + (threadIdx.x >> 6);
  int lane = threadIdx.x & 63;
  int c = lane * 2;
  float o0 = 0.f, o1 = 0.f;
#pragma unroll
  for (int hd = 0; hd < 2; hd++) {
    float a0 = 0.f, a1 = 0.f, Z = 0.f;
#pragma unroll
    for (int s = 0; s < ATT_S; s++) {
      const float* Op = Opart + ((size_t)hd * ATT_S + s) * NN * DH;
      float2 t = *(const float2*)&Op[(size_t)row * DH + c];
      a0 += t.x; a1 += t.y;
      Z += Zpart[((size_t)hd * ATT_S + s) * NN + row];
    }
    float invZ = 1.f / Z;
    float v0 = a0 * invZ, v1 = a1 * invZ;
    v0 = fmaxf(v0, 0.2f * v0);
    v1 = fmaxf(v1, 0.2f * v1);
    float ss = v0 * v0 + v1 * v1;
#pragma unroll
    for (int off = 32; off >= 1; off >>= 1) ss += __shfl_xor(ss, off, 64);
    float sc_ = 1.f / fmaxf(sqrtf(ss), 1e-12f);
    o0 += 0.5f * (v0 * sc_ + bvec[hd * DH + c]);
    o1 += 0.5f * (v1 * sc_ + bvec[hd * DH + c + 1]);
  }
  if (DO_ELU) {
    o0 = (o0 > 0.f) ? o0 : expm1f(o0);
    o1 = (o1 > 0.f) ? o1 : expm1f(o1);
  }
  float2 st = {o0, o1};
  *(float2*)&out[(size_t)row * DH + c] = st;
}

// ---------------- gather tf/tg rows into GRU input ----------------
__global__ __launch_bounds__(256) void gather_k(const float* __restrict__ tf, const float* __restrict__ tg,
                                                const int* __restrict__ ts, float* __restrict__ hx_t) {
  int idx = blockIdx.x * 256 + threadIdx.x;
  int e = idx >> 5, c = idx & 31;
  int src = (c < 16) ? ts[e * 2] : ts[e * 2 + 1];
  float v = (c < 16) ? tf[(size_t)src * 16 + c] : tg[(size_t)src * 16 + (c - 16)];
  hx_t[idx] = v;
}

// ---------------- GRU gate fusion ----------------
__global__ __launch_bounds__(256) void gru_gate_k(const float* __restrict__ gi, const float* __restrict__ gh,
                                                  const float* __restrict__ hprev, float* __restrict__ hout) {
  int idx = blockIdx.x * 256 + threadIdx.x;
  int b = idx >> 7, c = idx & 127;
  const float* gib = gi + (size_t)b * 384;
  const float* ghb = gh + (size_t)b * 384;
  float ir = gib[c], iz = gib[128 + c], in_ = gib[256 + c];
  float hr = ghb[c], hz = ghb[128 + c], hn = ghb[256 + c];
  float rr = 1.f / (1.f + __expf(-(ir + hr)));
  float zz = 1.f / (1.f + __expf(-(iz + hz)));
  float nn_ = tanhf(in_ + rr * hn);
  hout[idx] = (1.f - zz) * nn_ + zz * hprev[idx];
}

// ---------------- temporal attention pooling ----------------
__global__ __launch_bounds__(256) void attpool_k(const float* __restrict__ z, const float* __restrict__ y,
                                                 float* __restrict__ o) {
  int idx = blockIdx.x * 256 + threadIdx.x;
  const size_t S = (size_t)NN * DH;
  float z0 = z[idx], z1 = z[idx + S], z2 = z[idx + 2 * S], z3 = z[idx + 3 * S];
  float mx = fmaxf(fmaxf(z0, z1), fmaxf(z2, z3));
  float e0 = __expf(z0 - mx), e1 = __expf(z1 - mx), e2 = __expf(z2 - mx), e3 = __expf(z3 - mx);
  float inv = 1.f / (e0 + e1 + e2 + e3);
  o[idx] = (e0 * y[idx] + e1 * y[idx + S] + e2 * y[idx + 2 * S] + e3 * y[idx + 3 * S]) * inv;
}

// ---------------- final projection ----------------
__global__ __launch_bounds__(256) void final_k(const float* __restrict__ at, const float* __restrict__ fow,
                                               const float* __restrict__ fob, float* __restrict__ out) {
  int row = blockIdx.x * 4 + (threadIdx.x >> 6);
  int lane = threadIdx.x & 63;
  const float* ar = at + (size_t)row * DH;
  float p = ar[lane] * fow[lane] + ar[lane + 64] * fow[lane + 64];
#pragma unroll
  for (int off = 32; off >= 1; off >>= 1) p += __shfl_xor(p, off, 64);
  if (lane == 0) out[row] = p + fob[0];
}

// ---------------- host ----------------
static inline void run_gemm(int act, const float* A, const float* B, const float* bias, float* C,
                            int M, int N, int K, hipStream_t s) {
  dim3 g((N + 63) / 64, M / 64), b(256);
  if (act == 0) gemm_mfma_k<0><<<g, b, 0, s>>>(A, B, bias, C, M, N, K);
  else          gemm_mfma_k<1><<<g, b, 0, s>>>(A, B, bias, C, M, N, K);
}

extern "C" void kernel_launch(void* const* d_in, const int* in_sizes, int n_in,
                              void* d_out, int out_size, void* d_ws, size_t ws_size,
                              hipStream_t stream) {
  const float* x[4]  = {(const float*)d_in[0], (const float*)d_in[1], (const float*)d_in[2], (const float*)d_in[3]};
  const int* adj     = (const int*)d_in[4];
  const int* tsample = (const int*)d_in[5];
  const float* nw[4] = {(const float*)d_in[6], (const float*)d_in[8], (const float*)d_in[10], (const float*)d_in[12]};
  const float* nb[4] = {(const float*)d_in[7], (const float*)d_in[9], (const float*)d_in[11], (const float*)d_in[13]};
  const float* W1 = (const float*)d_in[14];
  const float* a1 = (const float*)d_in[15];
  const float* b1 = (const float*)d_in[16];
  const float* W2 = (const float*)d_in[17];
  const float* a2 = (const float*)d_in[18];
  const float* b2 = (const float*)d_in[19];
  const float* tfw1 = (const float*)d_in[20]; const float* tfb1 = (const float*)d_in[21];
  const float* tfw2 = (const float*)d_in[22]; const float* tfb2 = (const float*)d_in[23];
  const float* tgw1 = (const float*)d_in[24]; const float* tgb1 = (const float*)d_in[25];
  const float* tgw2 = (const float*)d_in[26]; const float* tgb2 = (const float*)d_in[27];
  const float* wih0 = (const float*)d_in[28]; const float* whh0 = (const float*)d_in[29];
  const float* bih0 = (const float*)d_in[30]; const float* bhh0 = (const float*)d_in[31];
  const float* wih1 = (const float*)d_in[32]; const float* whh1 = (const float*)d_in[33];
  const float* bih1 = (const float*)d_in[34]; const float* bhh1 = (const float*)d_in[35];
  const float* attw = (const float*)d_in[36]; const float* attb = (const float*)d_in[37];
  const float* fow  = (const float*)d_in[38]; const float* fob  = (const float*)d_in[39];
  float* out = (float*)d_out;

  // workspace layout (bump allocator, 256B aligned)
  char* base = (char*)d_ws;
  size_t off = 0;
  auto alloc = [&](size_t bytes) -> void* {
    void* p = base + off;
    off += (bytes + 255) & ~(size_t)255;
    return p;
  };
  const size_t SN = (size_t)NN * DH;
  unsigned long long* mbits = (unsigned long long*)alloc((size_t)NN * 64 * 8);  // 2MB
  float* ebuf = (float*)alloc((size_t)NN * 256 * 4);  // 4MB  (reused as zbuf later)
  float* h0   = (float*)alloc(SN * 4);                // 2MB
  float* h1   = (float*)alloc(SN * 4);                // 2MB
  float* el   = (float*)alloc((size_t)2 * NN * 4);
  float* er   = (float*)alloc((size_t)2 * NN * 4);
  float* mrowb= (float*)alloc((size_t)2 * NN * 4);
  float* bufA = (float*)alloc(SN * 4);                // embed
  float* bufB = (float*)alloc(SN * 4);                // layer-1 out (post-ELU)
  float* tmp1 = (float*)alloc((size_t)NN * 64 * 4);
  float* tfb_ = (float*)alloc((size_t)NN * 16 * 4);
  float* tgb_ = (float*)alloc((size_t)NN * 16 * 4);
  float* hx   = (float*)alloc((size_t)TP * NN * 32 * 4);  // 2MB
  float* y0   = (float*)alloc((size_t)TP * SN * 4);       // 8MB  } Opart aliases y0+y1
  float* y1   = (float*)alloc((size_t)TP * SN * 4);       // 8MB  }
  float* gi   = (float*)alloc((size_t)NN * 384 * 4);      // 6MB  } Zpart / zatt alias gi(+gh)
  float* gh   = (float*)alloc((size_t)NN * 384 * 4);      // 6MB
  float* Opart = y0;       // [2][ATT_S][NN][DH] fp32 = 16MB, dead before GRU writes y0/y1
  float* Zpart = gi;       // [2][ATT_S][NN] = 128KB, dead before GRU writes gi
  float* zatt   = gi;      // pooling scratch (8MB over gi+gh, post-GRU)
  float* zbuf   = ebuf;    // GRU h0 zeros
  float* attout = h0;      // pooled output

  const int TD[4] = {933, 303, 683, 798};

  pack_mask_k<<<(NN * 64) / 4, 256, 0, stream>>>(adj, mbits);

  for (int t = 0; t < TP; t++) {
    // e = x_t @ nw_t + nb_t    [4096 x 256]
    run_gemm(0, x[t], nw[t], nb[t], ebuf, NN, 256, TD[t], stream);

    // ---- GAT layer 1 (2 heads, mean, +ELU) ----
    run_gemm(0, ebuf, W1, nullptr, h0, NN, DH, 256, stream);
    run_gemm(0, ebuf, W1 + (size_t)256 * DH, nullptr, h1, NN, DH, 256, stream);
    eler_k<<<dim3(NN / 4, 2), 256, 0, stream>>>(h0, h1, a1, el, er);
    rowmax_k<<<dim3(NN / 4, 2), 256, 0, stream>>>(el, er, mbits, mrowb);
    gat_mfma_k<<<dim3(ATT_S, NN / ATT_BM, 2), 256, 0, stream>>>(h0, h1, el, er, mrowb, mbits, Opart, Zpart);
    combine_k<1><<<NN / 4, 256, 0, stream>>>(Opart, Zpart, b1, bufB);

    // ---- GAT layer 2 (2 heads, mean) ----
    run_gemm(0, bufB, W2, nullptr, h0, NN, DH, DH, stream);
    run_gemm(0, bufB, W2 + (size_t)DH * DH, nullptr, h1, NN, DH, DH, stream);
    eler_k<<<dim3(NN / 4, 2), 256, 0, stream>>>(h0, h1, a2, el, er);
    rowmax_k<<<dim3(NN / 4, 2), 256, 0, stream>>>(el, er, mbits, mrowb);
    gat_mfma_k<<<dim3(ATT_S, NN / ATT_BM, 2), 256, 0, stream>>>(h0, h1, el, er, mrowb, mbits, Opart, Zpart);
    combine_k<0><<<NN / 4, 256, 0, stream>>>(Opart, Zpart, b2, bufA);

    // ---- tf / tg MLPs (leaky 0.01) ----
    run_gemm(1, bufA, tfw1, tfb1, tmp1, NN, 64, DH, stream);
    run_gemm(1, tmp1, tfw2, tfb2, tfb_, NN, 16, 64, stream);
    run_gemm(1, bufA, tgw1, tgb1, tmp1, NN, 64, DH, stream);
    run_gemm(1, tmp1, tgw2, tgb2, tgb_, NN, 16, 64, stream);
    gather_k<<<(NN * 32) / 256, 256, 0, stream>>>(tfb_, tgb_, tsample, hx + (size_t)t * NN * 32);
  }

  // GRU h0 = zeros
  fill0_k<<<(int)(SN / 256), 256, 0, stream>>>(zbuf, (int)SN);

  // GRU layer 0: input 32 -> 128
  for (int t = 0; t < TP; t++) {
    const float* hprev = (t == 0) ? zbuf : (y0 + (size_t)(t - 1) * SN);
    run_gemm(0, hx + (size_t)t * NN * 32, wih0, bih0, gi, NN, 384, 32, stream);
    run_gemm(0, hprev, whh0, bhh0, gh, NN, 384, DH, stream);
    gru_gate_k<<<(int)(SN / 256), 256, 0, stream>>>(gi, gh, hprev, y0 + (size_t)t * SN);
  }
  // GRU layer 1: 128 -> 128
  for (int t = 0; t < TP; t++) {
    const float* hprev = (t == 0) ? zbuf : (y1 + (size_t)(t - 1) * SN);
    run_gemm(0, y0 + (size_t)t * SN, wih1, bih1, gi, NN, 384, DH, stream);
    run_gemm(0, hprev, whh1, bhh1, gh, NN, 384, DH, stream);
    gru_gate_k<<<(int)(SN / 256), 256, 0, stream>>>(gi, gh, hprev, y1 + (size_t)t * SN);
  }

  // temporal attention pooling: one batched GEMM over all 4 timesteps
  run_gemm(0, y1, attw, attb, zatt, TP * NN, DH, DH, stream);
  attpool_k<<<(int)(SN / 256), 256, 0, stream>>>(zatt, y1, attout);
  final_k<<<NN / 4, 256, 0, stream>>>(attout, fow, fob, out);
}

// Round 9
// 1355.561 us; speedup vs baseline: 4.0355x; 1.1480x over previous
//
#include <hip/hip_runtime.h>
#include <cstdint>
#include <cstddef>

// ---------------- constants ----------------
#define NN 4096          // nodes
#define DH 128           // H1 == H2 == GRU_H
#define TP 4
#define ATT_S 4          // j-splits in attention
#define ATT_BM 64        // rows per attention block

typedef _Float16 f16x8 __attribute__((ext_vector_type(8)));
typedef float f32x4 __attribute__((ext_vector_type(4)));

// ---------------- pack adjacency into bitmask ----------------
__global__ __launch_bounds__(256) void pack_mask_k(const int* __restrict__ adj,
                                                   unsigned long long* __restrict__ mb) {
  int w = blockIdx.x * 4 + (threadIdx.x >> 6);
  int lane = threadIdx.x & 63;
  int v = adj[(size_t)w * 64 + lane];
  unsigned long long bits = __ballot(v > 0);
  if (lane == 0) mb[w] = bits;
}

// ---------------- MFMA fp32-via-f16-split GEMM: C = act(A@B + bias) ----------------
// 64x64 tile, BK=64, 4 waves (2x2), each wave a 32x32 quadrant.
// BHEAD=1: B is [2][K][128] (two head matrices concatenated along N=256).
template <int ACT, int BHEAD>
__global__ __launch_bounds__(256) void gemm_mfma_k(const float* __restrict__ A, const float* __restrict__ B,
                                                   const float* __restrict__ bias, float* __restrict__ C,
                                                   int M, int N, int K) {
  __shared__ _Float16 AH[64 * 64], AL[64 * 64];
  __shared__ _Float16 BH[64 * 64], BL[64 * 64];
  const int tid = threadIdx.x;
  const int bm = blockIdx.y * 64, bn = blockIdx.x * 64;
  const int arow = tid >> 2, akc = (tid & 3) * 16;
  const int bcol = tid & 63, bkc = (tid >> 6) * 16;
  const int w = tid >> 6, lane = tid & 63;
  const int wm = w >> 1, wn = w & 1;
  const int l15 = lane & 15, l4 = lane >> 4;
  f32x4 acc[2][2] = {};

  const float* Bp = B;
  int bcb = bn;
  if (BHEAD) { int hd = bn >> 7; Bp = B + (size_t)hd * K * 128; bcb = bn & 127; }
  const int ldb = BHEAD ? 128 : N;

  for (int k0 = 0; k0 < K; k0 += 64) {
    __syncthreads();
    // ---- stage A tile (f16 hi/lo split, swizzled) ----
    {
      const float* ar = A + (size_t)(bm + arow) * K;
      f16x8 hv[2], lv[2];
#pragma unroll
      for (int e = 0; e < 16; e++) {
        int gk = k0 + akc + e;
        float v = (gk < K) ? ar[gk] : 0.f;
        _Float16 hi = (_Float16)v;
        hv[e >> 3][e & 7] = hi;
        lv[e >> 3][e & 7] = (_Float16)(v - (float)hi);
      }
#pragma unroll
      for (int hf = 0; hf < 2; hf++) {
        int byt = ((arow * 64 + akc + hf * 8) * 2) ^ ((arow & 7) << 4);
        *(f16x8*)((char*)AH + byt) = hv[hf];
        *(f16x8*)((char*)AL + byt) = lv[hf];
      }
    }
    // ---- stage B^T tile ----
    {
      f16x8 hv[2], lv[2];
      const bool cok = (bcb + bcol) < ldb;
#pragma unroll
      for (int e = 0; e < 16; e++) {
        int gk = k0 + bkc + e;
        float v = (gk < K && cok) ? Bp[(size_t)gk * ldb + bcb + bcol] : 0.f;
        _Float16 hi = (_Float16)v;
        hv[e >> 3][e & 7] = hi;
        lv[e >> 3][e & 7] = (_Float16)(v - (float)hi);
      }
#pragma unroll
      for (int hf = 0; hf < 2; hf++) {
        int byt = ((bcol * 64 + bkc + hf * 8) * 2) ^ ((bcol & 7) << 4);
        *(f16x8*)((char*)BH + byt) = hv[hf];
        *(f16x8*)((char*)BL + byt) = lv[hf];
      }
    }
    __syncthreads();
    // ---- MFMA ----
#pragma unroll
    for (int kf = 0; kf < 2; kf++) {
      f16x8 ah[2], al[2], bh[2], bl[2];
#pragma unroll
      for (int m2 = 0; m2 < 2; m2++) {
        int r = wm * 32 + m2 * 16 + l15;
        int byt = ((r * 64 + kf * 32 + l4 * 8) * 2) ^ ((r & 7) << 4);
        ah[m2] = *(const f16x8*)((const char*)AH + byt);
        al[m2] = *(const f16x8*)((const char*)AL + byt);
      }
#pragma unroll
      for (int nf = 0; nf < 2; nf++) {
        int c = wn * 32 + nf * 16 + l15;
        int byt = ((c * 64 + kf * 32 + l4 * 8) * 2) ^ ((c & 7) << 4);
        bh[nf] = *(const f16x8*)((const char*)BH + byt);
        bl[nf] = *(const f16x8*)((const char*)BL + byt);
      }
#pragma unroll
      for (int m2 = 0; m2 < 2; m2++)
#pragma unroll
        for (int nf = 0; nf < 2; nf++) {
          acc[m2][nf] = __builtin_amdgcn_mfma_f32_16x16x32_f16(ah[m2], bh[nf], acc[m2][nf], 0, 0, 0);
          acc[m2][nf] = __builtin_amdgcn_mfma_f32_16x16x32_f16(ah[m2], bl[nf], acc[m2][nf], 0, 0, 0);
          acc[m2][nf] = __builtin_amdgcn_mfma_f32_16x16x32_f16(al[m2], bh[nf], acc[m2][nf], 0, 0, 0);
        }
    }
  }
  // ---- epilogue (C/D layout: col=lane&15, row=(lane>>4)*4+q) ----
#pragma unroll
  for (int m2 = 0; m2 < 2; m2++)
#pragma unroll
    for (int nf = 0; nf < 2; nf++) {
      int c = bn + wn * 32 + nf * 16 + l15;
      if (c < N) {
        float bv = bias ? bias[c] : 0.f;
#pragma unroll
        for (int q = 0; q < 4; q++) {
          int r = bm + wm * 32 + m2 * 16 + l4 * 4 + q;
          float v = acc[m2][nf][q] + bv;
          if (ACT == 1) v = (v >= 0.f) ? v : 0.01f * v;
          C[(size_t)r * N + c] = v;
        }
      }
    }
}

// ---------------- el/er for both heads (hcat layout [NN][256]) ----------------
__global__ __launch_bounds__(256) void eler_k(const float* __restrict__ hcat, const float* __restrict__ a,
                                              float* __restrict__ el, float* __restrict__ er) {
  int head = blockIdx.y;
  const float* ah = a + (size_t)head * 256;
  int row = blockIdx.x * 4 + (threadIdx.x >> 6);
  int lane = threadIdx.x & 63;
  const float* hr = hcat + (size_t)row * 256 + head * 128;
  float h0 = hr[lane], h1 = hr[lane + 64];
  float pe = h0 * ah[lane] + h1 * ah[lane + 64];
  float pr = h0 * ah[128 + lane] + h1 * ah[192 + lane];
#pragma unroll
  for (int off = 32; off >= 1; off >>= 1) {
    pe += __shfl_xor(pe, off, 64);
    pr += __shfl_xor(pr, off, 64);
  }
  if (lane == 0) { el[(size_t)head * NN + row] = pe; er[(size_t)head * NN + row] = pr; }
}

// ---------------- exact masked row max: m = leaky(el + max_masked(er)) ----------------
__global__ __launch_bounds__(256) void rowmax_k(const float* __restrict__ el, const float* __restrict__ er,
                                                const unsigned long long* __restrict__ mb,
                                                float* __restrict__ mrow) {
  int head = blockIdx.y;
  int row = blockIdx.x * 4 + (threadIdx.x >> 6);
  int lane = threadIdx.x & 63;
  const float* erh = er + (size_t)head * NN;
  const unsigned long long* mr = mb + (size_t)row * 64;
  float mx = -INFINITY;
  for (int i = 0; i < 64; i++) {
    unsigned long long w = mr[i];
    float v = erh[i * 64 + lane];
    mx = fmaxf(mx, ((w >> lane) & 1ull) ? v : -INFINITY);
  }
#pragma unroll
  for (int off = 32; off >= 1; off >>= 1) mx = fmaxf(mx, __shfl_xor(mx, off, 64));
  if (lane == 0) {
    float s = el[(size_t)head * NN + row] + mx;
    mrow[(size_t)head * NN + row] = fmaxf(s, 0.2f * s);
  }
}

// ---------------- pre-split + pre-transpose + pre-swizzle H into f16 tiles ----------------
// Output tiles: per (head, jblk) a 16KB byte image matching gat's swizzled LDS layout:
//   element (c,k) of H^T at byte ((c*64+k)*2) ^ ((c&7)<<4).
__global__ __launch_bounds__(256) void hsplit_k(const float* __restrict__ hcat,
                                                _Float16* __restrict__ HTH, _Float16* __restrict__ HTL) {
  const int jblk = blockIdx.x;   // 0..63
  const int head = blockIdx.y;   // 0..1
  const int tid = threadIdx.x;
  const int c = tid & 127;
  const size_t tileBase = ((size_t)head * (NN / 64) + jblk) * 8192;  // f16 elements
#pragma unroll
  for (int kq = 0; kq < 4; kq++) {
    int k0 = (tid >> 7) * 32 + kq * 8;
    f16x8 hv, lv;
#pragma unroll
    for (int e = 0; e < 8; e++) {
      float v = hcat[(size_t)(jblk * 64 + k0 + e) * 256 + head * 128 + c];
      _Float16 hi = (_Float16)v;
      hv[e] = hi;
      lv[e] = (_Float16)(v - (float)hi);
    }
    int byt = ((c * 64 + k0) * 2) ^ ((c & 7) << 4);
    *(f16x8*)((char*)(HTH + tileBase) + byt) = hv;
    *(f16x8*)((char*)(HTL + tileBase) + byt) = lv;
  }
}

// ---------------- MFMA flash-GAT: accumulate O_part = P @ H, Z_part ----------------
// H tiles pre-split/swizzled in global (hsplit_k); staging is a pure 16B-chunk copy.
__global__ __launch_bounds__(256) void gat_mfma_k(const _Float16* __restrict__ HTH_g,
                                                  const _Float16* __restrict__ HTL_g,
                                                  const float* __restrict__ el, const float* __restrict__ er,
                                                  const float* __restrict__ mrow,
                                                  const unsigned long long* __restrict__ mb,
                                                  float* __restrict__ Opart, float* __restrict__ Zpart) {
  const int split = blockIdx.x;
  const int mblk = blockIdx.y;
  const int head = blockIdx.z;
  const float* elh = el + (size_t)head * NN;
  const float* erh = er + (size_t)head * NN;
  const float* mh = mrow + (size_t)head * NN;
  float* Op = Opart + ((size_t)head * ATT_S + split) * NN * DH;
  float* Zp = Zpart + ((size_t)head * ATT_S + split) * NN;

  __shared__ _Float16 PH[ATT_BM * 64];   // 8 KB
  __shared__ _Float16 PL[ATT_BM * 64];   // 8 KB
  __shared__ _Float16 HH[128 * 64];      // 16 KB (byte image from HTH_g)
  __shared__ _Float16 HL[128 * 64];      // 16 KB
  __shared__ float zred[ATT_BM][4];

  const int tid = threadIdx.x;
  const int prow = tid >> 2;
  const int pk0 = (tid & 3) * 16;
  const int grow = mblk * ATT_BM + prow;
  const float el_r = elh[grow];
  const float m_r = mh[grow];
  const int w = tid >> 6, lane = tid & 63;
  const int wm = w >> 1, wn = w & 1;
  const int l15 = lane & 15, l4 = lane >> 4;

  f32x4 acc[2][4] = {};
  float zacc = 0.f;
  const int jbase = split * (NN / ATT_S);

  for (int jt = 0; jt < NN / ATT_S; jt += 64) {
    const int j0 = jbase + jt;
    const int jblk = j0 >> 6;
    const char* srcH = (const char*)(HTH_g + ((size_t)head * (NN / 64) + jblk) * 8192);
    const char* srcL = (const char*)(HTL_g + ((size_t)head * (NN / 64) + jblk) * 8192);
    __syncthreads();   // previous MFMA done reading LDS

    // ---- issue H-tile loads (latency hidden under P-compute) ----
    f16x8 rh[4], rl[4];
#pragma unroll
    for (int i = 0; i < 4; i++) {
      rh[i] = *(const f16x8*)(srcH + (tid + i * 256) * 16);
      rl[i] = *(const f16x8*)(srcL + (tid + i * 256) * 16);
    }

    // ---- compute P tile (64 x 64), f16 hi/lo, swizzled row-major ----
    {
      unsigned long long wbits = mb[(size_t)grow * 64 + jblk];
      float er_v[16];
#pragma unroll
      for (int q = 0; q < 4; q++) {
        float4 t = *(const float4*)&erh[j0 + pk0 + q * 4];
        er_v[q * 4 + 0] = t.x; er_v[q * 4 + 1] = t.y;
        er_v[q * 4 + 2] = t.z; er_v[q * 4 + 3] = t.w;
      }
      f16x8 hv[2], lv[2];
#pragma unroll
      for (int e = 0; e < 16; e++) {
        float sr = el_r + er_v[e];
        float s = fmaxf(sr, 0.2f * sr);
        float p = ((wbits >> (pk0 + e)) & 1ull) ? __expf(s - m_r) : 0.f;
        zacc += p;
        _Float16 hi = (_Float16)p;
        hv[e >> 3][e & 7] = hi;
        lv[e >> 3][e & 7] = (_Float16)(p - (float)hi);
      }
#pragma unroll
      for (int half = 0; half < 2; half++) {
        int byt = (((prow * 64) + pk0 + half * 8) * 2) ^ ((prow & 7) << 4);
        *(f16x8*)((char*)PH + byt) = hv[half];
        *(f16x8*)((char*)PL + byt) = lv[half];
      }
    }

    // ---- write H tile to LDS (verbatim byte copy; swizzle baked into data) ----
#pragma unroll
    for (int i = 0; i < 4; i++) {
      *(f16x8*)((char*)HH + (tid + i * 256) * 16) = rh[i];
      *(f16x8*)((char*)HL + (tid + i * 256) * 16) = rl[i];
    }
    __syncthreads();

    // ---- MFMA: acc += Phi*Hhi + Phi*Hlo + Plo*Hhi ----
#pragma unroll
    for (int kf = 0; kf < 2; kf++) {
      f16x8 ah[2], al[2];
#pragma unroll
      for (int m2 = 0; m2 < 2; m2++) {
        int ar = wm * 32 + m2 * 16 + l15;
        int ak = kf * 32 + l4 * 8;
        int ab = ((ar * 64 + ak) * 2) ^ ((ar & 7) << 4);
        ah[m2] = *(const f16x8*)((const char*)PH + ab);
        al[m2] = *(const f16x8*)((const char*)PL + ab);
      }
#pragma unroll
      for (int nf = 0; nf < 4; nf++) {
        int bc = wn * 64 + nf * 16 + l15;
        int bk = kf * 32 + l4 * 8;
        int bb = ((bc * 64 + bk) * 2) ^ ((bc & 7) << 4);
        f16x8 bh = *(const f16x8*)((const char*)HH + bb);
        f16x8 bl = *(const f16x8*)((const char*)HL + bb);
#pragma unroll
        for (int m2 = 0; m2 < 2; m2++) {
          acc[m2][nf] = __builtin_amdgcn_mfma_f32_16x16x32_f16(ah[m2], bh, acc[m2][nf], 0, 0, 0);
          acc[m2][nf] = __builtin_amdgcn_mfma_f32_16x16x32_f16(ah[m2], bl, acc[m2][nf], 0, 0, 0);
          acc[m2][nf] = __builtin_amdgcn_mfma_f32_16x16x32_f16(al[m2], bh, acc[m2][nf], 0, 0, 0);
        }
      }
    }
  }

  // ---- Z reduce ----
  zred[prow][tid & 3] = zacc;
  __syncthreads();
  if (tid < ATT_BM) {
    float z = zred[tid][0] + zred[tid][1] + zred[tid][2] + zred[tid][3];
    Zp[mblk * ATT_BM + tid] = z;
  }

  // ---- O_part store (C/D layout: col=lane&15, row=(lane>>4)*4+q) ----
#pragma unroll
  for (int m2 = 0; m2 < 2; m2++)
#pragma unroll
    for (int nf = 0; nf < 4; nf++)
#pragma unroll
      for (int q = 0; q < 4; q++) {
        int r = mblk * ATT_BM + wm * 32 + m2 * 16 + l4 * 4 + q;
        int c = wn * 64 + nf * 16 + l15;
        Op[(size_t)r * DH + c] = acc[m2][nf][q];
      }
}

// ---------------- combine partials -> head mean (+optional ELU) ----------------
template <int DO_ELU>
__global__ __launch_bounds__(256) void combine_k(const float* __restrict__ Opart,
                                                 const float* __restrict__ Zpart,
                                                 const float* __restrict__ bvec,
                                                 float* __restrict__ out) {
  int row = blockIdx.x * 4 + (threadIdx.x >> 6);
  int lane = threadIdx.x & 63;
  int c = lane * 2;
  float o0 = 0.f, o1 = 0.f;
#pragma unroll
  for (int hd = 0; hd < 2; hd++) {
    float a0 = 0.f, a1 = 0.f, Z = 0.f;
#pragma unroll
    for (int s = 0; s < ATT_S; s++) {
      const float* Op = Opart + ((size_t)hd * ATT_S + s) * NN * DH;
      float2 t = *(const float2*)&Op[(size_t)row * DH + c];
      a0 += t.x; a1 += t.y;
      Z += Zpart[((size_t)hd * ATT_S + s) * NN + row];
    }
    float invZ = 1.f / Z;
    float v0 = a0 * invZ, v1 = a1 * invZ;
    v0 = fmaxf(v0, 0.2f * v0);
    v1 = fmaxf(v1, 0.2f * v1);
    float ss = v0 * v0 + v1 * v1;
#pragma unroll
    for (int off = 32; off >= 1; off >>= 1) ss += __shfl_xor(ss, off, 64);
    float sc_ = 1.f / fmaxf(sqrtf(ss), 1e-12f);
    o0 += 0.5f * (v0 * sc_ + bvec[hd * DH + c]);
    o1 += 0.5f * (v1 * sc_ + bvec[hd * DH + c + 1]);
  }
  if (DO_ELU) {
    o0 = (o0 > 0.f) ? o0 : expm1f(o0);
    o1 = (o1 > 0.f) ? o1 : expm1f(o1);
  }
  float2 st = {o0, o1};
  *(float2*)&out[(size_t)row * DH + c] = st;
}

// ---------------- gather tf/tg rows into GRU input ----------------
__global__ __launch_bounds__(256) void gather_k(const float* __restrict__ tf, const float* __restrict__ tg,
                                                const int* __restrict__ ts, float* __restrict__ hx_t) {
  int idx = blockIdx.x * 256 + threadIdx.x;
  int e = idx >> 5, c = idx & 31;
  int src = (c < 16) ? ts[e * 2] : ts[e * 2 + 1];
  float v = (c < 16) ? tf[(size_t)src * 16 + c] : tg[(size_t)src * 16 + (c - 16)];
  hx_t[idx] = v;
}

// ---------------- GRU gate fusion ----------------
__global__ __launch_bounds__(256) void gru_gate_k(const float* __restrict__ gi, const float* __restrict__ gh,
                                                  const float* __restrict__ hprev, float* __restrict__ hout) {
  int idx = blockIdx.x * 256 + threadIdx.x;
  int b = idx >> 7, c = idx & 127;
  const float* gib = gi + (size_t)b * 384;
  const float* ghb = gh + (size_t)b * 384;
  float ir = gib[c], iz = gib[128 + c], in_ = gib[256 + c];
  float hr = ghb[c], hz = ghb[128 + c], hn = ghb[256 + c];
  float rr = 1.f / (1.f + __expf(-(ir + hr)));
  float zz = 1.f / (1.f + __expf(-(iz + hz)));
  float nn_ = tanhf(in_ + rr * hn);
  hout[idx] = (1.f - zz) * nn_ + zz * hprev[idx];
}

// ---------------- GRU gate, t=0 (hprev = 0 -> gh = bhh) ----------------
__global__ __launch_bounds__(256) void gru_gate0_k(const float* __restrict__ gi, const float* __restrict__ bhh,
                                                   float* __restrict__ hout) {
  int idx = blockIdx.x * 256 + threadIdx.x;
  int b = idx >> 7, c = idx & 127;
  const float* gib = gi + (size_t)b * 384;
  float ir = gib[c], iz = gib[128 + c], in_ = gib[256 + c];
  float hr = bhh[c], hz = bhh[128 + c], hn = bhh[256 + c];
  float rr = 1.f / (1.f + __expf(-(ir + hr)));
  float zz = 1.f / (1.f + __expf(-(iz + hz)));
  float nn_ = tanhf(in_ + rr * hn);
  hout[idx] = (1.f - zz) * nn_;
}

// ---------------- temporal attention pooling ----------------
__global__ __launch_bounds__(256) void attpool_k(const float* __restrict__ z, const float* __restrict__ y,
                                                 float* __restrict__ o) {
  int idx = blockIdx.x * 256 + threadIdx.x;
  const size_t S = (size_t)NN * DH;
  float z0 = z[idx], z1 = z[idx + S], z2 = z[idx + 2 * S], z3 = z[idx + 3 * S];
  float mx = fmaxf(fmaxf(z0, z1), fmaxf(z2, z3));
  float e0 = __expf(z0 - mx), e1 = __expf(z1 - mx), e2 = __expf(z2 - mx), e3 = __expf(z3 - mx);
  float inv = 1.f / (e0 + e1 + e2 + e3);
  o[idx] = (e0 * y[idx] + e1 * y[idx + S] + e2 * y[idx + 2 * S] + e3 * y[idx + 3 * S]) * inv;
}

// ---------------- final projection ----------------
__global__ __launch_bounds__(256) void final_k(const float* __restrict__ at, const float* __restrict__ fow,
                                               const float* __restrict__ fob, float* __restrict__ out) {
  int row = blockIdx.x * 4 + (threadIdx.x >> 6);
  int lane = threadIdx.x & 63;
  const float* ar = at + (size_t)row * DH;
  float p = ar[lane] * fow[lane] + ar[lane + 64] * fow[lane + 64];
#pragma unroll
  for (int off = 32; off >= 1; off >>= 1) p += __shfl_xor(p, off, 64);
  if (lane == 0) out[row] = p + fob[0];
}

// ---------------- host ----------------
static inline void run_gemm(int act, const float* A, const float* B, const float* bias, float* C,
                            int M, int N, int K, hipStream_t s) {
  dim3 g((N + 63) / 64, M / 64), b(256);
  if (act == 0) gemm_mfma_k<0, 0><<<g, b, 0, s>>>(A, B, bias, C, M, N, K);
  else          gemm_mfma_k<1, 0><<<g, b, 0, s>>>(A, B, bias, C, M, N, K);
}
static inline void run_proj(const float* A, const float* B, float* C, int K, hipStream_t s) {
  // B = [2][K][128]; C = [NN][256]
  gemm_mfma_k<0, 1><<<dim3(4, NN / 64), 256, 0, s>>>(A, B, nullptr, C, NN, 256, K);
}

extern "C" void kernel_launch(void* const* d_in, const int* in_sizes, int n_in,
                              void* d_out, int out_size, void* d_ws, size_t ws_size,
                              hipStream_t stream) {
  const float* x[4]  = {(const float*)d_in[0], (const float*)d_in[1], (const float*)d_in[2], (const float*)d_in[3]};
  const int* adj     = (const int*)d_in[4];
  const int* tsample = (const int*)d_in[5];
  const float* nw[4] = {(const float*)d_in[6], (const float*)d_in[8], (const float*)d_in[10], (const float*)d_in[12]};
  const float* nb[4] = {(const float*)d_in[7], (const float*)d_in[9], (const float*)d_in[11], (const float*)d_in[13]};
  const float* W1 = (const float*)d_in[14];
  const float* a1 = (const float*)d_in[15];
  const float* b1 = (const float*)d_in[16];
  const float* W2 = (const float*)d_in[17];
  const float* a2 = (const float*)d_in[18];
  const float* b2 = (const float*)d_in[19];
  const float* tfw1 = (const float*)d_in[20]; const float* tfb1 = (const float*)d_in[21];
  const float* tfw2 = (const float*)d_in[22]; const float* tfb2 = (const float*)d_in[23];
  const float* tgw1 = (const float*)d_in[24]; const float* tgb1 = (const float*)d_in[25];
  const float* tgw2 = (const float*)d_in[26]; const float* tgb2 = (const float*)d_in[27];
  const float* wih0 = (const float*)d_in[28]; const float* whh0 = (const float*)d_in[29];
  const float* bih0 = (const float*)d_in[30]; const float* bhh0 = (const float*)d_in[31];
  const float* wih1 = (const float*)d_in[32]; const float* whh1 = (const float*)d_in[33];
  const float* bih1 = (const float*)d_in[34]; const float* bhh1 = (const float*)d_in[35];
  const float* attw = (const float*)d_in[36]; const float* attb = (const float*)d_in[37];
  const float* fow  = (const float*)d_in[38]; const float* fob  = (const float*)d_in[39];
  float* out = (float*)d_out;

  // workspace layout (bump allocator, 256B aligned)
  char* base = (char*)d_ws;
  size_t off = 0;
  auto alloc = [&](size_t bytes) -> void* {
    void* p = base + off;
    off += (bytes + 255) & ~(size_t)255;
    return p;
  };
  const size_t SN = (size_t)NN * DH;
  unsigned long long* mbits = (unsigned long long*)alloc((size_t)NN * 64 * 8);  // 2MB
  float* ebuf = (float*)alloc((size_t)NN * 256 * 4);  // 4MB; reused as HTH/HTL after W-proj consumes it
  float* hcat = (float*)alloc((size_t)NN * 256 * 4);  // 4MB  [NN][256] both heads
  float* el   = (float*)alloc((size_t)2 * NN * 4);
  float* er   = (float*)alloc((size_t)2 * NN * 4);
  float* mrowb= (float*)alloc((size_t)2 * NN * 4);
  float* bufA = (float*)alloc(SN * 4);                // embed
  float* bufB = (float*)alloc(SN * 4);                // layer-1 out (post-ELU)
  float* tmp1 = (float*)alloc((size_t)NN * 64 * 4);
  float* tfb_ = (float*)alloc((size_t)NN * 16 * 4);
  float* tgb_ = (float*)alloc((size_t)NN * 16 * 4);
  float* hx   = (float*)alloc((size_t)TP * NN * 32 * 4);  // 2MB
  float* y0   = (float*)alloc((size_t)TP * SN * 4);       // 8MB  } Opart aliases y0+y1
  float* y1   = (float*)alloc((size_t)TP * SN * 4);       // 8MB  }
  float* gi   = (float*)alloc((size_t)NN * 384 * 4);      // 6MB  } Zpart / zatt alias gi(+gh)
  float* gh   = (float*)alloc((size_t)NN * 384 * 4);      // 6MB
  float* Opart = y0;       // [2][ATT_S][NN][DH] fp32 = 16MB, dead before GRU writes y0/y1
  float* Zpart = gi;       // [2][ATT_S][NN] = 128KB, dead before GRU writes gi
  float* zatt   = gi;      // pooling scratch (8MB over gi+gh, post-GRU)
  float* attout = hcat;    // pooled output (hcat dead post-GAT)
  // H pre-split tiles alias ebuf (4MB = 2MB + 2MB): ebuf is consumed by the W-proj
  // GEMM before hsplit_k writes these (stream-ordered).
  _Float16* HTH = (_Float16*)ebuf;
  _Float16* HTL = HTH + (size_t)2 * NN * 128;   // 1M f16 = 2MB each

  const int TD[4] = {933, 303, 683, 798};

  pack_mask_k<<<(NN * 64) / 4, 256, 0, stream>>>(adj, mbits);

  for (int t = 0; t < TP; t++) {
    // e = x_t @ nw_t + nb_t    [4096 x 256]
    run_gemm(0, x[t], nw[t], nb[t], ebuf, NN, 256, TD[t], stream);

    // ---- GAT layer 1 (2 heads, mean, +ELU) ----
    run_proj(ebuf, W1, hcat, 256, stream);     // both heads, reads ebuf fully
    hsplit_k<<<dim3(NN / 64, 2), 256, 0, stream>>>(hcat, HTH, HTL);   // overwrites ebuf area
    eler_k<<<dim3(NN / 4, 2), 256, 0, stream>>>(hcat, a1, el, er);
    rowmax_k<<<dim3(NN / 4, 2), 256, 0, stream>>>(el, er, mbits, mrowb);
    gat_mfma_k<<<dim3(ATT_S, NN / ATT_BM, 2), 256, 0, stream>>>(HTH, HTL, el, er, mrowb, mbits, Opart, Zpart);
    combine_k<1><<<NN / 4, 256, 0, stream>>>(Opart, Zpart, b1, bufB);

    // ---- GAT layer 2 (2 heads, mean) ----
    run_proj(bufB, W2, hcat, 128, stream);
    hsplit_k<<<dim3(NN / 64, 2), 256, 0, stream>>>(hcat, HTH, HTL);
    eler_k<<<dim3(NN / 4, 2), 256, 0, stream>>>(hcat, a2, el, er);
    rowmax_k<<<dim3(NN / 4, 2), 256, 0, stream>>>(el, er, mbits, mrowb);
    gat_mfma_k<<<dim3(ATT_S, NN / ATT_BM, 2), 256, 0, stream>>>(HTH, HTL, el, er, mrowb, mbits, Opart, Zpart);
    combine_k<0><<<NN / 4, 256, 0, stream>>>(Opart, Zpart, b2, bufA);

    // ---- tf / tg MLPs (leaky 0.01) ----
    run_gemm(1, bufA, tfw1, tfb1, tmp1, NN, 64, DH, stream);
    run_gemm(1, tmp1, tfw2, tfb2, tfb_, NN, 16, 64, stream);
    run_gemm(1, bufA, tgw1, tgb1, tmp1, NN, 64, DH, stream);
    run_gemm(1, tmp1, tgw2, tgb2, tgb_, NN, 16, 64, stream);
    gather_k<<<(NN * 32) / 256, 256, 0, stream>>>(tfb_, tgb_, tsample, hx + (size_t)t * NN * 32);
  }

  // GRU layer 0: input 32 -> 128   (t=0: hprev=0 -> gh = bhh, no GEMM)
  run_gemm(0, hx, wih0, bih0, gi, NN, 384, 32, stream);
  gru_gate0_k<<<(int)(SN / 256), 256, 0, stream>>>(gi, bhh0, y0);
  for (int t = 1; t < TP; t++) {
    const float* hprev = y0 + (size_t)(t - 1) * SN;
    run_gemm(0, hx + (size_t)t * NN * 32, wih0, bih0, gi, NN, 384, 32, stream);
    run_gemm(0, hprev, whh0, bhh0, gh, NN, 384, DH, stream);
    gru_gate_k<<<(int)(SN / 256), 256, 0, stream>>>(gi, gh, hprev, y0 + (size_t)t * SN);
  }
  // GRU layer 1: 128 -> 128
  run_gemm(0, y0, wih1, bih1, gi, NN, 384, DH, stream);
  gru_gate0_k<<<(int)(SN / 256), 256, 0, stream>>>(gi, bhh1, y1);
  for (int t = 1; t < TP; t++) {
    const float* hprev = y1 + (size_t)(t - 1) * SN;
    run_gemm(0, y0 + (size_t)t * SN, wih1, bih1, gi, NN, 384, DH, stream);
    run_gemm(0, hprev, whh1, bhh1, gh, NN, 384, DH, stream);
    gru_gate_k<<<(int)(SN / 256), 256, 0, stream>>>(gi, gh, hprev, y1 + (size_t)t * SN);
  }

  // temporal attention pooling: one batched GEMM over all 4 timesteps
  run_gemm(0, y1, attw, attb, zatt, TP * NN, DH, DH, stream);
  attpool_k<<<(int)(SN / 256), 256, 0, stream>>>(zatt, y1, attout);
  final_k<<<NN / 4, 256, 0, stream>>>(attout, fow, fob, out);
}